// Round 9
// baseline (199.220 us; speedup 1.0000x reference)
//
#include <hip/hip_runtime.h>
#include <hip/hip_bf16.h>

#define BB 4
#define NN 4096
#define DD 512
#define BND (BB*NN)   // 16384

typedef __attribute__((ext_vector_type(8))) short bf16x8;
typedef __attribute__((ext_vector_type(4))) float f32x4;

// ---------- bf16 helpers ----------
__device__ __forceinline__ float b2f(unsigned int u){
    union { unsigned int u; float f; } c; c.u = u << 16; return c.f;
}
__device__ __forceinline__ unsigned short f2b(float f){
    union { float f; unsigned int u; } c; c.f = f;
    unsigned int r = c.u + 0x7fffu + ((c.u >> 16) & 1u);   // RNE
    return (unsigned short)(r >> 16);
}
__device__ __forceinline__ unsigned int pack2(float lo, float hi){
    __hip_bfloat162 h = __float22bfloat162_rn(make_float2(lo, hi));
    return *reinterpret_cast<unsigned int*>(&h);
}
__device__ __forceinline__ void unpack8(uint4 v, float* o){
    o[0]=b2f(v.x & 0xffffu); o[1]=b2f(v.x >> 16);
    o[2]=b2f(v.y & 0xffffu); o[3]=b2f(v.y >> 16);
    o[4]=b2f(v.z & 0xffffu); o[5]=b2f(v.z >> 16);
    o[6]=b2f(v.w & 0xffffu); o[7]=b2f(v.w >> 16);
}

// async global->LDS, 16B/lane; lds dest is wave-uniform base + lane*16
__device__ __forceinline__ void gload16(const void* g, void* l){
    __builtin_amdgcn_global_load_lds(
        (const __attribute__((address_space(1))) unsigned int*)g,
        (__attribute__((address_space(3))) unsigned int*)l,
        16, 0, 0);
}

// ---- XOR-swizzled staging (linear LDS dest, inverse-swizzled global src) ----
// LDS rows of 64 bf16 (8 chunks x 16B). Phys chunk c of row r holds logical chunk c^(r&7).
__device__ __forceinline__ void stage128(const unsigned short* g, size_t gstride,
                                         unsigned short* lds, int w, int l){
    const int rr = l >> 3;                      // row within 8-group == r&7
    const int sc = ((l & 7) ^ rr) * 8;          // swizzled source col (elems)
    const unsigned short* src = g + (size_t)(w*32 + rr) * gstride + sc;
    unsigned short* dst = lds + w*32*64;
    #pragma unroll
    for (int blk = 0; blk < 4; ++blk)
        gload16(src + (size_t)blk*8*gstride, dst + blk*8*64);
}
__device__ __forceinline__ void stage64(const unsigned short* g, size_t gstride,
                                        unsigned short* lds, int w, int l){
    const int rr = l >> 3;
    const int sc = ((l & 7) ^ rr) * 8;
    const unsigned short* src = g + (size_t)(w*16 + rr) * gstride + sc;
    unsigned short* dst = lds + w*16*64;
    #pragma unroll
    for (int blk = 0; blk < 2; ++blk)
        gload16(src + (size_t)blk*8*gstride, dst + blk*8*64);
}

// ---------- sin/cos table ----------
__global__ void k_sincos(float* __restrict__ sc){
    int t = blockIdx.x * 256 + threadIdx.x;
    if (t < NN){
        float idx = 1.5707963267948966f * ((float)(t + 1) / (float)NN);
        sc[t]      = sinf(idx);
        sc[NN + t] = cosf(idx);
    }
}

// ---------- fp32 -> bf16 bulk convert ----------
__global__ void k_cvt(const float* __restrict__ in, unsigned short* __restrict__ out, int n8){
    int t = blockIdx.x * 256 + threadIdx.x;
    if (t < n8){
        float4 a = reinterpret_cast<const float4*>(in)[t*2];
        float4 b = reinterpret_cast<const float4*>(in)[t*2+1];
        uint4 st;
        st.x = pack2(a.x, a.y); st.y = pack2(a.z, a.w);
        st.z = pack2(b.x, b.y); st.w = pack2(b.z, b.w);
        reinterpret_cast<uint4*>(out)[t] = st;
    }
}

// ---------- q,k,v projections, 2-phase pipelined (double-buffered LDS) ----------
// which 0: Q2=[sin*q|cos*q] row-major [BND][1024]
// which 1: Ktsc=[sin*k; cos*k] transposed [1024][BND]
// which 2: Vt transposed [512][BND]
__global__ __launch_bounds__(256) void k_qkv(
    const unsigned short* __restrict__ Xb,
    const unsigned short* __restrict__ Wqb,
    const unsigned short* __restrict__ Wkb,
    const unsigned short* __restrict__ Wvb,
    const float* __restrict__ sc,
    unsigned short* __restrict__ Q2,
    unsigned short* __restrict__ Ktsc,
    unsigned short* __restrict__ Vt)
{
    __shared__ __align__(16) unsigned short As[2][128*64];
    __shared__ __align__(16) unsigned short Bs[2][128*64];

    const int which = blockIdx.z;
    const unsigned short* W = (which == 0) ? Wqb : ((which == 1) ? Wkb : Wvb);

    const int tid = threadIdx.x;
    const int r0 = blockIdx.x * 128;
    const int c0 = blockIdx.y * 128;
    const int w  = tid >> 6, l = tid & 63;
    const int wr = (w >> 1) * 64, wc = (w & 1) * 64;
    const int lm = l & 15, lq = l >> 4;

    const unsigned short* aP = Xb + (size_t)r0 * DD;
    const unsigned short* bP = W  + (size_t)c0 * DD;

    f32x4 acc[4][4];
    #pragma unroll
    for (int i = 0; i < 4; ++i)
        #pragma unroll
        for (int j = 0; j < 4; ++j)
            #pragma unroll
            for (int q = 0; q < 4; ++q) acc[i][j][q] = 0.0f;

    stage128(aP, DD, As[0], w, l);
    stage128(bP, DD, Bs[0], w, l);
    __syncthreads();

    const int NT = DD / 64;     // 8
    for (int t = 0; t < NT; ++t){
        const int cur = t & 1;
        if (t + 1 < NT){
            stage128(aP + (t+1)*64, DD, As[cur^1], w, l);
            stage128(bP + (t+1)*64, DD, Bs[cur^1], w, l);
        }
        bf16x8 af[4][2], bf[4][2];
        #pragma unroll
        for (int h = 0; h < 2; ++h){
            const int cs = ((h*4 + lq) ^ (lm & 7)) * 8;   // swizzled read chunk
            #pragma unroll
            for (int i = 0; i < 4; ++i){
                af[i][h] = *reinterpret_cast<const bf16x8*>(&As[cur][(wr + i*16 + lm)*64 + cs]);
                bf[i][h] = *reinterpret_cast<const bf16x8*>(&Bs[cur][(wc + i*16 + lm)*64 + cs]);
            }
        }
        #pragma unroll
        for (int h = 0; h < 2; ++h)
            #pragma unroll
            for (int i = 0; i < 4; ++i)
                #pragma unroll
                for (int j = 0; j < 4; ++j)
                    acc[i][j] = __builtin_amdgcn_mfma_f32_16x16x32_bf16(af[i][h], bf[j][h], acc[i][j], 0, 0, 0);
        __syncthreads();
    }

    if (which == 0){
        #pragma unroll
        for (int i = 0; i < 4; ++i){
            #pragma unroll
            for (int q = 0; q < 4; ++q){
                int row = r0 + wr + i*16 + lq*4 + q;
                int n = row & (NN - 1);
                float sn = sc[n], cn = sc[NN + n];
                size_t base = (size_t)row * 1024 + c0 + wc + lm;
                #pragma unroll
                for (int j = 0; j < 4; ++j){
                    float v = fmaxf(acc[i][j][q], 0.0f);
                    Q2[base + j*16]       = f2b(sn * v);
                    Q2[base + 512 + j*16] = f2b(cn * v);
                }
            }
        }
    } else if (which == 1){
        #pragma unroll
        for (int i = 0; i < 4; ++i){
            int rb = r0 + wr + i*16 + lq*4;       // 4 consecutive global rows
            int n  = rb & (NN - 1);
            float4 s4 = *reinterpret_cast<const float4*>(sc + n);
            float4 c4 = *reinterpret_cast<const float4*>(sc + NN + n);
            #pragma unroll
            for (int j = 0; j < 4; ++j){
                int d = c0 + wc + j*16 + lm;
                float v0 = fmaxf(acc[i][j][0], 0.f), v1 = fmaxf(acc[i][j][1], 0.f);
                float v2 = fmaxf(acc[i][j][2], 0.f), v3 = fmaxf(acc[i][j][3], 0.f);
                uint2 stS, stC;
                stS.x = pack2(v0*s4.x, v1*s4.y); stS.y = pack2(v2*s4.z, v3*s4.w);
                stC.x = pack2(v0*c4.x, v1*c4.y); stC.y = pack2(v2*c4.z, v3*c4.w);
                *reinterpret_cast<uint2*>(Ktsc + (size_t)d * BND + rb)         = stS;
                *reinterpret_cast<uint2*>(Ktsc + (size_t)(512 + d) * BND + rb) = stC;
            }
        }
    } else {
        #pragma unroll
        for (int i = 0; i < 4; ++i){
            int rb = r0 + wr + i*16 + lq*4;
            #pragma unroll
            for (int j = 0; j < 4; ++j){
                int d = c0 + wc + j*16 + lm;
                uint2 st;
                st.x = pack2(acc[i][j][0], acc[i][j][1]);
                st.y = pack2(acc[i][j][2], acc[i][j][3]);
                *reinterpret_cast<uint2*>(Vt + (size_t)d * BND + rb) = st;
            }
        }
    }
}

// ---------- kvp[b][m][dp] += sum_n Vt[m,n]*Ktsc[dp,n]; split-8 over n; 2-phase ----------
__global__ __launch_bounds__(256) void k_kv(
    const unsigned short* __restrict__ Vt,
    const unsigned short* __restrict__ Ktsc,
    float* __restrict__ kvp)
{
    __shared__ __align__(16) unsigned short As[2][128*64];
    __shared__ __align__(16) unsigned short Bs[2][128*64];

    const int tid = threadIdx.x;
    const int m0  = blockIdx.x * 128;
    const int b   = blockIdx.z >> 3;
    const int sp  = blockIdx.z & 7;
    const int dp0 = ((blockIdx.y + sp) & 7) * 128;   // stagger across sp
    const int cb  = b * NN + sp * 512;
    const int w  = tid >> 6, l = tid & 63;
    const int wr = (w >> 1) * 64, wc = (w & 1) * 64;
    const int lm = l & 15, lq = l >> 4;

    const unsigned short* aP = Vt   + (size_t)m0  * BND + cb;
    const unsigned short* bP = Ktsc + (size_t)dp0 * BND + cb;

    f32x4 acc[4][4];
    #pragma unroll
    for (int i = 0; i < 4; ++i)
        #pragma unroll
        for (int j = 0; j < 4; ++j)
            #pragma unroll
            for (int q = 0; q < 4; ++q) acc[i][j][q] = 0.0f;

    stage128(aP, BND, As[0], w, l);
    stage128(bP, BND, Bs[0], w, l);
    __syncthreads();

    const int NT = 512 / 64;    // 8
    for (int t = 0; t < NT; ++t){
        const int cur = t & 1;
        if (t + 1 < NT){
            stage128(aP + (t+1)*64, BND, As[cur^1], w, l);
            stage128(bP + (t+1)*64, BND, Bs[cur^1], w, l);
        }
        bf16x8 af[4][2], bf[4][2];
        #pragma unroll
        for (int h = 0; h < 2; ++h){
            const int cs = ((h*4 + lq) ^ (lm & 7)) * 8;
            #pragma unroll
            for (int i = 0; i < 4; ++i){
                af[i][h] = *reinterpret_cast<const bf16x8*>(&As[cur][(wr + i*16 + lm)*64 + cs]);
                bf[i][h] = *reinterpret_cast<const bf16x8*>(&Bs[cur][(wc + i*16 + lm)*64 + cs]);
            }
        }
        #pragma unroll
        for (int h = 0; h < 2; ++h)
            #pragma unroll
            for (int i = 0; i < 4; ++i)
                #pragma unroll
                for (int j = 0; j < 4; ++j)
                    acc[i][j] = __builtin_amdgcn_mfma_f32_16x16x32_bf16(af[i][h], bf[j][h], acc[i][j], 0, 0, 0);
        __syncthreads();
    }

    // C rows = m, cols = dp. kvp[b][m][dp], dp lane-contiguous -> coalesced atomics.
    #pragma unroll
    for (int i = 0; i < 4; ++i){
        #pragma unroll
        for (int q = 0; q < 4; ++q){
            int m = m0 + wr + i*16 + lq*4 + q;
            float* rowp = kvp + ((size_t)b*512 + m) * 1024;
            #pragma unroll
            for (int j = 0; j < 4; ++j){
                int dp = dp0 + wc + j*16 + lm;
                atomicAdd(rowp + dp, acc[i][j][q]);
            }
        }
    }
}

// ---------- ksum[b][dp] = sum_n Ktsc[dp, b*NN+n] ----------
__global__ __launch_bounds__(256) void k_ksum(
    const unsigned short* __restrict__ Ktsc,
    float* __restrict__ ksum)
{
    int b = blockIdx.y;
    int dp = blockIdx.x * 4 + (threadIdx.x >> 6);
    int l = threadIdx.x & 63;
    const unsigned short* row = Ktsc + (size_t)dp * BND + b * NN;
    float ss = 0.f;
    for (int c0 = 0; c0 < NN; c0 += 512){
        float f[8];
        unpack8(*reinterpret_cast<const uint4*>(row + c0 + l*8), f);
        #pragma unroll
        for (int u = 0; u < 8; ++u) ss += f[u];
    }
    #pragma unroll
    for (int off = 32; off; off >>= 1) ss += __shfl_xor(ss, off);
    if (l == 0) ksum[b*1024 + dp] = ss;
}

// ---------- z[row] = 1/max(Q2[row,:].ksum[b,:], 1e-6) ----------
__global__ __launch_bounds__(256) void k_z(
    const unsigned short* __restrict__ Q2,
    const float* __restrict__ ksum,
    float* __restrict__ zden)
{
    int row  = blockIdx.x * 4 + (threadIdx.x >> 6);
    int lane = threadIdx.x & 63;
    int b = row >> 12;
    const unsigned short* qp = Q2 + (size_t)row * 1024 + lane * 16;
    float qf[16];
    unpack8(*reinterpret_cast<const uint4*>(qp), qf);
    unpack8(*reinterpret_cast<const uint4*>(qp + 8), qf + 8);
    const float* ks = ksum + (size_t)b*1024 + lane*16;
    float ps = 0.f;
    #pragma unroll
    for (int u = 0; u < 16; ++u) ps = fmaf(qf[u], ks[u], ps);
    #pragma unroll
    for (int off = 32; off; off >>= 1) ps += __shfl_xor(ps, off);
    if (lane == 0) zden[row] = 1.0f / fmaxf(ps, 1e-6f);
}

// ---------- out[n][m] = z * sum_dp Q2[n,dp]*kvb[b,m,dp]; 128x64 tiles; 2-phase ----------
__global__ __launch_bounds__(256) void k_out(
    const unsigned short* __restrict__ Q2,
    const unsigned short* __restrict__ kvb,
    const float* __restrict__ zden,
    float* __restrict__ Out)
{
    __shared__ __align__(16) unsigned short As[2][128*64];
    __shared__ __align__(16) unsigned short Bs[2][64*64];

    const int tid = threadIdx.x;
    const int r0 = blockIdx.x * 128;
    const int m0 = blockIdx.y * 64;
    const int b  = r0 >> 12;
    const int w  = tid >> 6, l = tid & 63;
    const int wr = (w >> 1) * 64, wc = (w & 1) * 32;
    const int lm = l & 15, lq = l >> 4;

    const unsigned short* aP = Q2 + (size_t)r0 * 1024;
    const unsigned short* bP = kvb + ((size_t)b*512 + m0) * 1024;

    f32x4 acc[4][2];
    #pragma unroll
    for (int i = 0; i < 4; ++i)
        #pragma unroll
        for (int j = 0; j < 2; ++j)
            #pragma unroll
            for (int q = 0; q < 4; ++q) acc[i][j][q] = 0.0f;

    stage128(aP, 1024, As[0], w, l);
    stage64 (bP, 1024, Bs[0], w, l);
    __syncthreads();

    const int NT = 1024 / 64;   // 16
    for (int t = 0; t < NT; ++t){
        const int cur = t & 1;
        if (t + 1 < NT){
            stage128(aP + (t+1)*64, 1024, As[cur^1], w, l);
            stage64 (bP + (t+1)*64, 1024, Bs[cur^1], w, l);
        }
        bf16x8 af[4][2], bf[2][2];
        #pragma unroll
        for (int h = 0; h < 2; ++h){
            const int cs = ((h*4 + lq) ^ (lm & 7)) * 8;
            #pragma unroll
            for (int i = 0; i < 4; ++i)
                af[i][h] = *reinterpret_cast<const bf16x8*>(&As[cur][(wr + i*16 + lm)*64 + cs]);
            #pragma unroll
            for (int j = 0; j < 2; ++j)
                bf[j][h] = *reinterpret_cast<const bf16x8*>(&Bs[cur][(wc + j*16 + lm)*64 + cs]);
        }
        #pragma unroll
        for (int h = 0; h < 2; ++h)
            #pragma unroll
            for (int i = 0; i < 4; ++i)
                #pragma unroll
                for (int j = 0; j < 2; ++j)
                    acc[i][j] = __builtin_amdgcn_mfma_f32_16x16x32_bf16(af[i][h], bf[j][h], acc[i][j], 0, 0, 0);
        __syncthreads();
    }

    #pragma unroll
    for (int i = 0; i < 4; ++i){
        #pragma unroll
        for (int q = 0; q < 4; ++q){
            int grow = r0 + wr + i*16 + lq*4 + q;
            int n = grow & (NN - 1);
            float z  = zden[grow];
            int hh = n >> 9;
            int ttb = (n & 511) * 8;
            #pragma unroll
            for (int j = 0; j < 2; ++j){
                int m = m0 + wc + j*16 + lm;
                int tt = ttb + (m >> 6);
                Out[((size_t)b*NN + tt) * DD + hh*64 + (m & 63)] = acc[i][j][q] * z;
            }
        }
    }
}

extern "C" void kernel_launch(void* const* d_in, const int* in_sizes, int n_in,
                              void* d_out, int out_size, void* d_ws, size_t ws_size,
                              hipStream_t stream)
{
    const float* X  = (const float*)d_in[0];
    const float* Wq = (const float*)d_in[1];
    const float* Wk = (const float*)d_in[2];
    const float* Wv = (const float*)d_in[3];
    float* Out = (float*)d_out;

    char* p = (char*)d_ws;
    float* sincos = (float*)p; p += (size_t)2*NN*sizeof(float);
    float* kvp    = (float*)p; p += (size_t)BB*512*1024*sizeof(float);   // 8 MB
    float* ksum   = (float*)p; p += (size_t)BB*1024*sizeof(float);
    float* zden   = (float*)p; p += (size_t)BND*sizeof(float);
    unsigned short* Xb   = (unsigned short*)p; p += (size_t)BND*DD*2;        // 16 MB
    unsigned short* Wqb  = (unsigned short*)p; p += (size_t)DD*DD*2;
    unsigned short* Wkb  = (unsigned short*)p; p += (size_t)DD*DD*2;
    unsigned short* Wvb  = (unsigned short*)p; p += (size_t)DD*DD*2;
    unsigned short* Q2   = (unsigned short*)p; p += (size_t)BND*1024*2;      // 32 MB
    unsigned short* Ktsc = (unsigned short*)p; p += (size_t)1024*BND*2;      // 32 MB
    unsigned short* Vt   = (unsigned short*)p; p += (size_t)512*BND*2;       // 16 MB
    unsigned short* kvb  = (unsigned short*)p; p += (size_t)BB*512*1024*2;   // 4 MB

    hipMemsetAsync(kvp, 0, (size_t)BB*512*1024*sizeof(float), stream);

    k_sincos<<<dim3(16), dim3(256), 0, stream>>>(sincos);
    k_cvt   <<<dim3(4096), dim3(256), 0, stream>>>(X,  Xb,  BND*DD/8);
    k_cvt   <<<dim3(128),  dim3(256), 0, stream>>>(Wq, Wqb, DD*DD/8);
    k_cvt   <<<dim3(128),  dim3(256), 0, stream>>>(Wk, Wkb, DD*DD/8);
    k_cvt   <<<dim3(128),  dim3(256), 0, stream>>>(Wv, Wvb, DD*DD/8);
    k_qkv   <<<dim3(BND/128, DD/128, 3), dim3(256), 0, stream>>>(Xb, Wqb, Wkb, Wvb, sincos, Q2, Ktsc, Vt);
    k_kv    <<<dim3(4, 8, 32), dim3(256), 0, stream>>>(Vt, Ktsc, kvp);
    k_ksum  <<<dim3(256, 4), dim3(256), 0, stream>>>(Ktsc, ksum);
    k_z     <<<dim3(BND/4), dim3(256), 0, stream>>>(Q2, ksum, zden);
    k_cvt   <<<dim3(1024), dim3(256), 0, stream>>>(kvp, kvb, BB*512*1024/8);
    k_out   <<<dim3(BND/128, 8), dim3(256), 0, stream>>>(Q2, kvb, zden, Out);
}

// Round 10
// 172.304 us; speedup vs baseline: 1.1562x; 1.1562x over previous
//
#include <hip/hip_runtime.h>
#include <hip/hip_bf16.h>

#define BB 4
#define NN 4096
#define DD 512
#define BND (BB*NN)   // 16384

typedef __attribute__((ext_vector_type(8))) short bf16x8;
typedef __attribute__((ext_vector_type(4))) float f32x4;

// ---------- bf16 helpers ----------
__device__ __forceinline__ float b2f(unsigned int u){
    union { unsigned int u; float f; } c; c.u = u << 16; return c.f;
}
__device__ __forceinline__ unsigned short f2b(float f){
    union { float f; unsigned int u; } c; c.f = f;
    unsigned int r = c.u + 0x7fffu + ((c.u >> 16) & 1u);   // RNE
    return (unsigned short)(r >> 16);
}
__device__ __forceinline__ unsigned int pack2(float lo, float hi){
    __hip_bfloat162 h = __float22bfloat162_rn(make_float2(lo, hi));
    return *reinterpret_cast<unsigned int*>(&h);
}
__device__ __forceinline__ void unpack8(uint4 v, float* o){
    o[0]=b2f(v.x & 0xffffu); o[1]=b2f(v.x >> 16);
    o[2]=b2f(v.y & 0xffffu); o[3]=b2f(v.y >> 16);
    o[4]=b2f(v.z & 0xffffu); o[5]=b2f(v.z >> 16);
    o[6]=b2f(v.w & 0xffffu); o[7]=b2f(v.w >> 16);
}

// async global->LDS, 16B/lane; lds dest is wave-uniform base + lane*16
__device__ __forceinline__ void gload16(const void* g, void* l){
    __builtin_amdgcn_global_load_lds(
        (const __attribute__((address_space(1))) unsigned int*)g,
        (__attribute__((address_space(3))) unsigned int*)l,
        16, 0, 0);
}

// ---- XOR-swizzled staging, 8-wave versions (512 threads) ----
// LDS rows of 64 bf16 (8 chunks x 16B). Phys chunk c of row r holds logical chunk c^(r&7).
// 128 rows x 64 cols, 8 waves -> 16 rows/wave (2 gloads):
__device__ __forceinline__ void stageA128(const unsigned short* g, size_t gstride,
                                          unsigned short* lds, int w, int l){
    const int rr = l >> 3;                      // 0..7 == row&7
    const int sc = ((l & 7) ^ rr) * 8;          // swizzled source chunk
    const unsigned short* src = g + (size_t)(w*16 + rr) * gstride + sc;
    unsigned short* dst = lds + w*16*64;
    gload16(src,                       dst);
    gload16(src + (size_t)8*gstride,   dst + 8*64);
}
// 64 rows x 64 cols, 8 waves -> 8 rows/wave (1 gload):
__device__ __forceinline__ void stageB64(const unsigned short* g, size_t gstride,
                                         unsigned short* lds, int w, int l){
    const int rr = l >> 3;
    const int sc = ((l & 7) ^ rr) * 8;
    gload16(g + (size_t)(w*8 + rr) * gstride + sc, lds + w*8*64);
}

// ---------- sin/cos table ----------
__global__ void k_sincos(float* __restrict__ sc){
    int t = blockIdx.x * 256 + threadIdx.x;
    if (t < NN){
        float idx = 1.5707963267948966f * ((float)(t + 1) / (float)NN);
        sc[t]      = sinf(idx);
        sc[NN + t] = cosf(idx);
    }
}

// ---------- fp32 -> bf16 bulk convert ----------
__global__ void k_cvt(const float* __restrict__ in, unsigned short* __restrict__ out, int n8){
    int t = blockIdx.x * 256 + threadIdx.x;
    if (t < n8){
        float4 a = reinterpret_cast<const float4*>(in)[t*2];
        float4 b = reinterpret_cast<const float4*>(in)[t*2+1];
        uint4 st;
        st.x = pack2(a.x, a.y); st.y = pack2(a.z, a.w);
        st.z = pack2(b.x, b.y); st.w = pack2(b.z, b.w);
        reinterpret_cast<uint4*>(out)[t] = st;
    }
}

// ---------- q,k,v projections, 8-wave, 2-phase dbuf ----------
// which 0: Q2=[sin*q|cos*q] row-major [BND][1024]
// which 1: Ktsc=[sin*k; cos*k] transposed [1024][BND]
// which 2: Vt transposed [512][BND]
__global__ __launch_bounds__(512) void k_qkv(
    const unsigned short* __restrict__ Xb,
    const unsigned short* __restrict__ Wqb,
    const unsigned short* __restrict__ Wkb,
    const unsigned short* __restrict__ Wvb,
    const float* __restrict__ sc,
    unsigned short* __restrict__ Q2,
    unsigned short* __restrict__ Ktsc,
    unsigned short* __restrict__ Vt)
{
    __shared__ __align__(16) unsigned short As[2][128*64];
    __shared__ __align__(16) unsigned short Bs[2][128*64];

    const int which = blockIdx.z;
    const unsigned short* W = (which == 0) ? Wqb : ((which == 1) ? Wkb : Wvb);

    const int tid = threadIdx.x;
    const int r0 = blockIdx.x * 128;
    const int c0 = blockIdx.y * 128;
    const int w  = tid >> 6, l = tid & 63;
    const int wr = (w >> 2) * 64;          // 2 row groups
    const int wc = (w & 3) * 32;           // 4 col groups
    const int lm = l & 15, lq = l >> 4;

    const unsigned short* aP = Xb + (size_t)r0 * DD;
    const unsigned short* bP = W  + (size_t)c0 * DD;

    f32x4 acc[4][2];
    #pragma unroll
    for (int i = 0; i < 4; ++i)
        #pragma unroll
        for (int j = 0; j < 2; ++j)
            #pragma unroll
            for (int q = 0; q < 4; ++q) acc[i][j][q] = 0.0f;

    stageA128(aP, DD, As[0], w, l);
    stageA128(bP, DD, Bs[0], w, l);
    __syncthreads();

    const int NT = DD / 64;     // 8
    for (int t = 0; t < NT; ++t){
        const int cur = t & 1;
        if (t + 1 < NT){
            stageA128(aP + (t+1)*64, DD, As[cur^1], w, l);
            stageA128(bP + (t+1)*64, DD, Bs[cur^1], w, l);
        }
        bf16x8 af[4][2], bf[2][2];
        #pragma unroll
        for (int h = 0; h < 2; ++h){
            const int cs = ((h*4 + lq) ^ (lm & 7)) * 8;   // swizzled read chunk
            #pragma unroll
            for (int i = 0; i < 4; ++i)
                af[i][h] = *reinterpret_cast<const bf16x8*>(&As[cur][(wr + i*16 + lm)*64 + cs]);
            #pragma unroll
            for (int j = 0; j < 2; ++j)
                bf[j][h] = *reinterpret_cast<const bf16x8*>(&Bs[cur][(wc + j*16 + lm)*64 + cs]);
        }
        #pragma unroll
        for (int h = 0; h < 2; ++h)
            #pragma unroll
            for (int i = 0; i < 4; ++i)
                #pragma unroll
                for (int j = 0; j < 2; ++j)
                    acc[i][j] = __builtin_amdgcn_mfma_f32_16x16x32_bf16(af[i][h], bf[j][h], acc[i][j], 0, 0, 0);
        __syncthreads();
    }

    if (which == 0){
        #pragma unroll
        for (int i = 0; i < 4; ++i){
            #pragma unroll
            for (int q = 0; q < 4; ++q){
                int row = r0 + wr + i*16 + lq*4 + q;
                int n = row & (NN - 1);
                float sn = sc[n], cn = sc[NN + n];
                size_t base = (size_t)row * 1024 + c0 + wc + lm;
                #pragma unroll
                for (int j = 0; j < 2; ++j){
                    float v = fmaxf(acc[i][j][q], 0.0f);
                    Q2[base + j*16]       = f2b(sn * v);
                    Q2[base + 512 + j*16] = f2b(cn * v);
                }
            }
        }
    } else if (which == 1){
        #pragma unroll
        for (int i = 0; i < 4; ++i){
            int rb = r0 + wr + i*16 + lq*4;       // 4 consecutive global rows
            int n  = rb & (NN - 1);
            float4 s4 = *reinterpret_cast<const float4*>(sc + n);
            float4 c4 = *reinterpret_cast<const float4*>(sc + NN + n);
            #pragma unroll
            for (int j = 0; j < 2; ++j){
                int d = c0 + wc + j*16 + lm;
                float v0 = fmaxf(acc[i][j][0], 0.f), v1 = fmaxf(acc[i][j][1], 0.f);
                float v2 = fmaxf(acc[i][j][2], 0.f), v3 = fmaxf(acc[i][j][3], 0.f);
                uint2 stS, stC;
                stS.x = pack2(v0*s4.x, v1*s4.y); stS.y = pack2(v2*s4.z, v3*s4.w);
                stC.x = pack2(v0*c4.x, v1*c4.y); stC.y = pack2(v2*c4.z, v3*c4.w);
                *reinterpret_cast<uint2*>(Ktsc + (size_t)d * BND + rb)         = stS;
                *reinterpret_cast<uint2*>(Ktsc + (size_t)(512 + d) * BND + rb) = stC;
            }
        }
    } else {
        #pragma unroll
        for (int i = 0; i < 4; ++i){
            int rb = r0 + wr + i*16 + lq*4;
            #pragma unroll
            for (int j = 0; j < 2; ++j){
                int d = c0 + wc + j*16 + lm;
                uint2 st;
                st.x = pack2(acc[i][j][0], acc[i][j][1]);
                st.y = pack2(acc[i][j][2], acc[i][j][3]);
                *reinterpret_cast<uint2*>(Vt + (size_t)d * BND + rb) = st;
            }
        }
    }
}

// ---------- kvp[b][m][dp] += sum_n Vt[m,n]*Ktsc[dp,n]; split-4; 8-wave; 2-phase ----------
__global__ __launch_bounds__(512) void k_kv(
    const unsigned short* __restrict__ Vt,
    const unsigned short* __restrict__ Ktsc,
    float* __restrict__ kvp)
{
    __shared__ __align__(16) unsigned short As[2][128*64];
    __shared__ __align__(16) unsigned short Bs[2][128*64];

    const int tid = threadIdx.x;
    const int m0  = blockIdx.x * 128;
    const int b   = blockIdx.z >> 2;
    const int sp  = blockIdx.z & 3;
    const int dp0 = ((blockIdx.y + sp) & 7) * 128;   // stagger across sp
    const int cb  = b * NN + sp * 1024;
    const int w  = tid >> 6, l = tid & 63;
    const int wr = (w >> 2) * 64, wc = (w & 3) * 32;
    const int lm = l & 15, lq = l >> 4;

    const unsigned short* aP = Vt   + (size_t)m0  * BND + cb;
    const unsigned short* bP = Ktsc + (size_t)dp0 * BND + cb;

    f32x4 acc[4][2];
    #pragma unroll
    for (int i = 0; i < 4; ++i)
        #pragma unroll
        for (int j = 0; j < 2; ++j)
            #pragma unroll
            for (int q = 0; q < 4; ++q) acc[i][j][q] = 0.0f;

    stageA128(aP, BND, As[0], w, l);
    stageA128(bP, BND, Bs[0], w, l);
    __syncthreads();

    const int NT = 1024 / 64;   // 16
    for (int t = 0; t < NT; ++t){
        const int cur = t & 1;
        if (t + 1 < NT){
            stageA128(aP + (t+1)*64, BND, As[cur^1], w, l);
            stageA128(bP + (t+1)*64, BND, Bs[cur^1], w, l);
        }
        bf16x8 af[4][2], bf[2][2];
        #pragma unroll
        for (int h = 0; h < 2; ++h){
            const int cs = ((h*4 + lq) ^ (lm & 7)) * 8;
            #pragma unroll
            for (int i = 0; i < 4; ++i)
                af[i][h] = *reinterpret_cast<const bf16x8*>(&As[cur][(wr + i*16 + lm)*64 + cs]);
            #pragma unroll
            for (int j = 0; j < 2; ++j)
                bf[j][h] = *reinterpret_cast<const bf16x8*>(&Bs[cur][(wc + j*16 + lm)*64 + cs]);
        }
        #pragma unroll
        for (int h = 0; h < 2; ++h)
            #pragma unroll
            for (int i = 0; i < 4; ++i)
                #pragma unroll
                for (int j = 0; j < 2; ++j)
                    acc[i][j] = __builtin_amdgcn_mfma_f32_16x16x32_bf16(af[i][h], bf[j][h], acc[i][j], 0, 0, 0);
        __syncthreads();
    }

    // C rows = m, cols = dp (lane-contiguous -> coalesced atomics)
    #pragma unroll
    for (int i = 0; i < 4; ++i){
        #pragma unroll
        for (int q = 0; q < 4; ++q){
            int m = m0 + wr + i*16 + lq*4 + q;
            float* rowp = kvp + ((size_t)b*512 + m) * 1024;
            #pragma unroll
            for (int j = 0; j < 2; ++j){
                int dp = dp0 + wc + j*16 + lm;
                atomicAdd(rowp + dp, acc[i][j][q]);
            }
        }
    }
}

// ---------- ksum[b][dp] = sum_n Ktsc[dp, b*NN+n] ----------
__global__ __launch_bounds__(256) void k_ksum(
    const unsigned short* __restrict__ Ktsc,
    float* __restrict__ ksum)
{
    int b = blockIdx.y;
    int dp = blockIdx.x * 4 + (threadIdx.x >> 6);
    int l = threadIdx.x & 63;
    const unsigned short* row = Ktsc + (size_t)dp * BND + b * NN;
    float ss = 0.f;
    for (int c0 = 0; c0 < NN; c0 += 512){
        float f[8];
        unpack8(*reinterpret_cast<const uint4*>(row + c0 + l*8), f);
        #pragma unroll
        for (int u = 0; u < 8; ++u) ss += f[u];
    }
    #pragma unroll
    for (int off = 32; off; off >>= 1) ss += __shfl_xor(ss, off);
    if (l == 0) ksum[b*1024 + dp] = ss;
}

// ---------- z[row] = 1/max(Q2[row,:].ksum[b,:], 1e-6) ----------
__global__ __launch_bounds__(256) void k_z(
    const unsigned short* __restrict__ Q2,
    const float* __restrict__ ksum,
    float* __restrict__ zden)
{
    int row  = blockIdx.x * 4 + (threadIdx.x >> 6);
    int lane = threadIdx.x & 63;
    int b = row >> 12;
    const unsigned short* qp = Q2 + (size_t)row * 1024 + lane * 16;
    float qf[16];
    unpack8(*reinterpret_cast<const uint4*>(qp), qf);
    unpack8(*reinterpret_cast<const uint4*>(qp + 8), qf + 8);
    const float* ks = ksum + (size_t)b*1024 + lane*16;
    float ps = 0.f;
    #pragma unroll
    for (int u = 0; u < 16; ++u) ps = fmaf(qf[u], ks[u], ps);
    #pragma unroll
    for (int off = 32; off; off >>= 1) ps += __shfl_xor(ps, off);
    if (lane == 0) zden[row] = 1.0f / fmaxf(ps, 1e-6f);
}

// ---------- out[n][m] = z * sum_dp Q2[n,dp]*kvb[b,m,dp]; 128x64 tiles; 8-wave; 2-phase ----------
__global__ __launch_bounds__(512) void k_out(
    const unsigned short* __restrict__ Q2,
    const unsigned short* __restrict__ kvb,
    const float* __restrict__ zden,
    float* __restrict__ Out)
{
    __shared__ __align__(16) unsigned short As[2][128*64];
    __shared__ __align__(16) unsigned short Bs[2][64*64];

    const int tid = threadIdx.x;
    const int r0 = blockIdx.x * 128;
    const int m0 = blockIdx.y * 64;
    const int b  = r0 >> 12;
    const int w  = tid >> 6, l = tid & 63;
    const int wr = (w >> 2) * 64, wc = (w & 3) * 16;
    const int lm = l & 15, lq = l >> 4;

    const unsigned short* aP = Q2 + (size_t)r0 * 1024;
    const unsigned short* bP = kvb + ((size_t)b*512 + m0) * 1024;

    f32x4 acc[4];
    #pragma unroll
    for (int i = 0; i < 4; ++i)
        #pragma unroll
        for (int q = 0; q < 4; ++q) acc[i][q] = 0.0f;

    stageA128(aP, 1024, As[0], w, l);
    stageB64 (bP, 1024, Bs[0], w, l);
    __syncthreads();

    const int NT = 1024 / 64;   // 16
    for (int t = 0; t < NT; ++t){
        const int cur = t & 1;
        if (t + 1 < NT){
            stageA128(aP + (t+1)*64, 1024, As[cur^1], w, l);
            stageB64 (bP + (t+1)*64, 1024, Bs[cur^1], w, l);
        }
        bf16x8 af[4][2], bf[2];
        #pragma unroll
        for (int h = 0; h < 2; ++h){
            const int cs = ((h*4 + lq) ^ (lm & 7)) * 8;
            #pragma unroll
            for (int i = 0; i < 4; ++i)
                af[i][h] = *reinterpret_cast<const bf16x8*>(&As[cur][(wr + i*16 + lm)*64 + cs]);
            bf[h] = *reinterpret_cast<const bf16x8*>(&Bs[cur][(wc + lm)*64 + cs]);
        }
        #pragma unroll
        for (int h = 0; h < 2; ++h)
            #pragma unroll
            for (int i = 0; i < 4; ++i)
                acc[i] = __builtin_amdgcn_mfma_f32_16x16x32_bf16(af[i][h], bf[h], acc[i], 0, 0, 0);
        __syncthreads();
    }

    #pragma unroll
    for (int i = 0; i < 4; ++i){
        #pragma unroll
        for (int q = 0; q < 4; ++q){
            int grow = r0 + wr + i*16 + lq*4 + q;
            int n = grow & (NN - 1);
            float z  = zden[grow];
            int hh = n >> 9;
            int ttb = (n & 511) * 8;
            int m = m0 + wc + lm;
            int tt = ttb + (m >> 6);
            Out[((size_t)b*NN + tt) * DD + hh*64 + (m & 63)] = acc[i][q] * z;
        }
    }
}

extern "C" void kernel_launch(void* const* d_in, const int* in_sizes, int n_in,
                              void* d_out, int out_size, void* d_ws, size_t ws_size,
                              hipStream_t stream)
{
    const float* X  = (const float*)d_in[0];
    const float* Wq = (const float*)d_in[1];
    const float* Wk = (const float*)d_in[2];
    const float* Wv = (const float*)d_in[3];
    float* Out = (float*)d_out;

    char* p = (char*)d_ws;
    float* sincos = (float*)p; p += (size_t)2*NN*sizeof(float);
    float* kvp    = (float*)p; p += (size_t)BB*512*1024*sizeof(float);   // 8 MB
    float* ksum   = (float*)p; p += (size_t)BB*1024*sizeof(float);
    float* zden   = (float*)p; p += (size_t)BND*sizeof(float);
    unsigned short* Xb   = (unsigned short*)p; p += (size_t)BND*DD*2;        // 16 MB
    unsigned short* Wqb  = (unsigned short*)p; p += (size_t)DD*DD*2;
    unsigned short* Wkb  = (unsigned short*)p; p += (size_t)DD*DD*2;
    unsigned short* Wvb  = (unsigned short*)p; p += (size_t)DD*DD*2;
    unsigned short* Q2   = (unsigned short*)p; p += (size_t)BND*1024*2;      // 32 MB
    unsigned short* Ktsc = (unsigned short*)p; p += (size_t)1024*BND*2;      // 32 MB
    unsigned short* Vt   = (unsigned short*)p; p += (size_t)512*BND*2;       // 16 MB
    unsigned short* kvb  = (unsigned short*)p; p += (size_t)BB*512*1024*2;   // 4 MB

    hipMemsetAsync(kvp, 0, (size_t)BB*512*1024*sizeof(float), stream);

    k_sincos<<<dim3(16), dim3(256), 0, stream>>>(sincos);
    k_cvt   <<<dim3(4096), dim3(256), 0, stream>>>(X,  Xb,  BND*DD/8);
    k_cvt   <<<dim3(128),  dim3(256), 0, stream>>>(Wq, Wqb, DD*DD/8);
    k_cvt   <<<dim3(128),  dim3(256), 0, stream>>>(Wk, Wkb, DD*DD/8);
    k_cvt   <<<dim3(128),  dim3(256), 0, stream>>>(Wv, Wvb, DD*DD/8);
    k_qkv   <<<dim3(BND/128, DD/128, 3), dim3(512), 0, stream>>>(Xb, Wqb, Wkb, Wvb, sincos, Q2, Ktsc, Vt);
    k_kv    <<<dim3(4, 8, BB*4), dim3(512), 0, stream>>>(Vt, Ktsc, kvp);
    k_ksum  <<<dim3(256, 4), dim3(256), 0, stream>>>(Ktsc, ksum);
    k_z     <<<dim3(BND/4), dim3(256), 0, stream>>>(Q2, ksum, zden);
    k_cvt   <<<dim3(1024), dim3(256), 0, stream>>>(kvp, kvb, BB*512*1024/8);
    k_out   <<<dim3(BND/128, DD/64), dim3(512), 0, stream>>>(Q2, kvb, zden, Out);
}

// Round 11
// 165.648 us; speedup vs baseline: 1.2027x; 1.0402x over previous
//
#include <hip/hip_runtime.h>
#include <hip/hip_bf16.h>

#define BB 4
#define NN 4096
#define DD 512
#define BND (BB*NN)   // 16384

typedef __attribute__((ext_vector_type(8))) short bf16x8;
typedef __attribute__((ext_vector_type(4))) float f32x4;

// ---------- bf16 helpers ----------
__device__ __forceinline__ float b2f(unsigned int u){
    union { unsigned int u; float f; } c; c.u = u << 16; return c.f;
}
__device__ __forceinline__ unsigned short f2b(float f){
    union { float f; unsigned int u; } c; c.f = f;
    unsigned int r = c.u + 0x7fffu + ((c.u >> 16) & 1u);   // RNE
    return (unsigned short)(r >> 16);
}
__device__ __forceinline__ unsigned int pack2(float lo, float hi){
    __hip_bfloat162 h = __float22bfloat162_rn(make_float2(lo, hi));
    return *reinterpret_cast<unsigned int*>(&h);
}
__device__ __forceinline__ void unpack8(uint4 v, float* o){
    o[0]=b2f(v.x & 0xffffu); o[1]=b2f(v.x >> 16);
    o[2]=b2f(v.y & 0xffffu); o[3]=b2f(v.y >> 16);
    o[4]=b2f(v.z & 0xffffu); o[5]=b2f(v.z >> 16);
    o[6]=b2f(v.w & 0xffffu); o[7]=b2f(v.w >> 16);
}

// async global->LDS, 16B/lane; lds dest is wave-uniform base + lane*16
__device__ __forceinline__ void gload16(const void* g, void* l){
    __builtin_amdgcn_global_load_lds(
        (const __attribute__((address_space(1))) unsigned int*)g,
        (__attribute__((address_space(3))) unsigned int*)l,
        16, 0, 0);
}

// counted vmcnt waits (T4): wait until <=N vmem ops outstanding
__device__ __forceinline__ void waitvm4(){ asm volatile("s_waitcnt vmcnt(4)" ::: "memory"); }
__device__ __forceinline__ void waitvm3(){ asm volatile("s_waitcnt vmcnt(3)" ::: "memory"); }
__device__ __forceinline__ void waitvm0(){ asm volatile("s_waitcnt vmcnt(0)" ::: "memory"); }

// ---- XOR-swizzled staging, 8-wave versions (512 threads) ----
// LDS rows of 64 bf16 (8 chunks x 16B). Phys chunk c of row r holds logical chunk c^(r&7).
// 128 rows x 64 cols, 8 waves -> 16 rows/wave (2 gloads):
__device__ __forceinline__ void stageA128(const unsigned short* g, size_t gstride,
                                          unsigned short* lds, int w, int l){
    const int rr = l >> 3;                      // 0..7 == row&7
    const int sc = ((l & 7) ^ rr) * 8;          // swizzled source chunk
    const unsigned short* src = g + (size_t)(w*16 + rr) * gstride + sc;
    unsigned short* dst = lds + w*16*64;
    gload16(src,                       dst);
    gload16(src + (size_t)8*gstride,   dst + 8*64);
}
// 64 rows x 64 cols, 8 waves -> 8 rows/wave (1 gload):
__device__ __forceinline__ void stageB64(const unsigned short* g, size_t gstride,
                                         unsigned short* lds, int w, int l){
    const int rr = l >> 3;
    const int sc = ((l & 7) ^ rr) * 8;
    gload16(g + (size_t)(w*8 + rr) * gstride + sc, lds + w*8*64);
}

// ---------- sin/cos table ----------
__global__ void k_sincos(float* __restrict__ sc){
    int t = blockIdx.x * 256 + threadIdx.x;
    if (t < NN){
        float idx = 1.5707963267948966f * ((float)(t + 1) / (float)NN);
        sc[t]      = sinf(idx);
        sc[NN + t] = cosf(idx);
    }
}

// ---------- fp32 -> bf16 bulk convert ----------
__global__ void k_cvt(const float* __restrict__ in, unsigned short* __restrict__ out, int n8){
    int t = blockIdx.x * 256 + threadIdx.x;
    if (t < n8){
        float4 a = reinterpret_cast<const float4*>(in)[t*2];
        float4 b = reinterpret_cast<const float4*>(in)[t*2+1];
        uint4 st;
        st.x = pack2(a.x, a.y); st.y = pack2(a.z, a.w);
        st.z = pack2(b.x, b.y); st.w = pack2(b.z, b.w);
        reinterpret_cast<uint4*>(out)[t] = st;
    }
}

// ---------- q,k,v projections, 8-wave, counted-vmcnt 2-phase ----------
// which 0: Q2=[sin*q|cos*q] row-major [BND][1024]
// which 1: Ktsc=[sin*k; cos*k] transposed [1024][BND]
// which 2: Vt transposed [512][BND]
__global__ __launch_bounds__(512) void k_qkv(
    const unsigned short* __restrict__ Xb,
    const unsigned short* __restrict__ Wqb,
    const unsigned short* __restrict__ Wkb,
    const unsigned short* __restrict__ Wvb,
    const float* __restrict__ sc,
    unsigned short* __restrict__ Q2,
    unsigned short* __restrict__ Ktsc,
    unsigned short* __restrict__ Vt)
{
    __shared__ __align__(16) unsigned short As[2][128*64];
    __shared__ __align__(16) unsigned short Bs[2][128*64];

    const int which = blockIdx.z;
    const unsigned short* W = (which == 0) ? Wqb : ((which == 1) ? Wkb : Wvb);

    const int tid = threadIdx.x;
    const int r0 = blockIdx.x * 128;
    const int c0 = blockIdx.y * 128;
    const int w  = tid >> 6, l = tid & 63;
    const int wr = (w >> 2) * 64;          // 2 row groups
    const int wc = (w & 3) * 32;           // 4 col groups
    const int lm = l & 15, lq = l >> 4;

    const unsigned short* aP = Xb + (size_t)r0 * DD;
    const unsigned short* bP = W  + (size_t)c0 * DD;

    f32x4 acc[4][2];
    #pragma unroll
    for (int i = 0; i < 4; ++i)
        #pragma unroll
        for (int j = 0; j < 2; ++j)
            #pragma unroll
            for (int q = 0; q < 4; ++q) acc[i][j][q] = 0.0f;

    stageA128(aP, DD, As[0], w, l);
    stageA128(bP, DD, Bs[0], w, l);

    const int NT = DD / 64;     // 8
    for (int t = 0; t < NT; ++t){
        const int cur = t & 1;
        if (t + 1 < NT){
            stageA128(aP + (t+1)*64, DD, As[cur^1], w, l);
            stageA128(bP + (t+1)*64, DD, Bs[cur^1], w, l);
            waitvm4();                      // stage(t) landed; stage(t+1) stays in flight
        } else {
            waitvm0();
        }
        __builtin_amdgcn_s_barrier();       // everyone's stage(t) landed
        bf16x8 af[4][2], bf[2][2];
        #pragma unroll
        for (int h = 0; h < 2; ++h){
            const int cs = ((h*4 + lq) ^ (lm & 7)) * 8;   // swizzled read chunk
            #pragma unroll
            for (int i = 0; i < 4; ++i)
                af[i][h] = *reinterpret_cast<const bf16x8*>(&As[cur][(wr + i*16 + lm)*64 + cs]);
            #pragma unroll
            for (int j = 0; j < 2; ++j)
                bf[j][h] = *reinterpret_cast<const bf16x8*>(&Bs[cur][(wc + j*16 + lm)*64 + cs]);
        }
        #pragma unroll
        for (int h = 0; h < 2; ++h)
            #pragma unroll
            for (int i = 0; i < 4; ++i)
                #pragma unroll
                for (int j = 0; j < 2; ++j)
                    acc[i][j] = __builtin_amdgcn_mfma_f32_16x16x32_bf16(af[i][h], bf[j][h], acc[i][j], 0, 0, 0);
        __builtin_amdgcn_s_barrier();       // all reads of buf[cur] consumed
    }

    if (which == 0){
        #pragma unroll
        for (int i = 0; i < 4; ++i){
            #pragma unroll
            for (int q = 0; q < 4; ++q){
                int row = r0 + wr + i*16 + lq*4 + q;
                int n = row & (NN - 1);
                float sn = sc[n], cn = sc[NN + n];
                size_t base = (size_t)row * 1024 + c0 + wc + lm;
                #pragma unroll
                for (int j = 0; j < 2; ++j){
                    float v = fmaxf(acc[i][j][q], 0.0f);
                    Q2[base + j*16]       = f2b(sn * v);
                    Q2[base + 512 + j*16] = f2b(cn * v);
                }
            }
        }
    } else if (which == 1){
        #pragma unroll
        for (int i = 0; i < 4; ++i){
            int rb = r0 + wr + i*16 + lq*4;       // 4 consecutive global rows
            int n  = rb & (NN - 1);
            float4 s4 = *reinterpret_cast<const float4*>(sc + n);
            float4 c4 = *reinterpret_cast<const float4*>(sc + NN + n);
            #pragma unroll
            for (int j = 0; j < 2; ++j){
                int d = c0 + wc + j*16 + lm;
                float v0 = fmaxf(acc[i][j][0], 0.f), v1 = fmaxf(acc[i][j][1], 0.f);
                float v2 = fmaxf(acc[i][j][2], 0.f), v3 = fmaxf(acc[i][j][3], 0.f);
                uint2 stS, stC;
                stS.x = pack2(v0*s4.x, v1*s4.y); stS.y = pack2(v2*s4.z, v3*s4.w);
                stC.x = pack2(v0*c4.x, v1*c4.y); stC.y = pack2(v2*c4.z, v3*c4.w);
                *reinterpret_cast<uint2*>(Ktsc + (size_t)d * BND + rb)         = stS;
                *reinterpret_cast<uint2*>(Ktsc + (size_t)(512 + d) * BND + rb) = stC;
            }
        }
    } else {
        #pragma unroll
        for (int i = 0; i < 4; ++i){
            int rb = r0 + wr + i*16 + lq*4;
            #pragma unroll
            for (int j = 0; j < 2; ++j){
                int d = c0 + wc + j*16 + lm;
                uint2 st;
                st.x = pack2(acc[i][j][0], acc[i][j][1]);
                st.y = pack2(acc[i][j][2], acc[i][j][3]);
                *reinterpret_cast<uint2*>(Vt + (size_t)d * BND + rb) = st;
            }
        }
    }
}

// ---------- kvp[b][m][dp] += sum_n Vt[m,n]*Ktsc[dp,n]; split-4; 8-wave; counted vmcnt ----------
__global__ __launch_bounds__(512) void k_kv(
    const unsigned short* __restrict__ Vt,
    const unsigned short* __restrict__ Ktsc,
    float* __restrict__ kvp)
{
    __shared__ __align__(16) unsigned short As[2][128*64];
    __shared__ __align__(16) unsigned short Bs[2][128*64];

    const int tid = threadIdx.x;
    const int m0  = blockIdx.x * 128;
    const int b   = blockIdx.z >> 2;
    const int sp  = blockIdx.z & 3;
    const int dp0 = ((blockIdx.y + sp) & 7) * 128;   // stagger across sp
    const int cb  = b * NN + sp * 1024;
    const int w  = tid >> 6, l = tid & 63;
    const int wr = (w >> 2) * 64, wc = (w & 3) * 32;
    const int lm = l & 15, lq = l >> 4;

    const unsigned short* aP = Vt   + (size_t)m0  * BND + cb;
    const unsigned short* bP = Ktsc + (size_t)dp0 * BND + cb;

    f32x4 acc[4][2];
    #pragma unroll
    for (int i = 0; i < 4; ++i)
        #pragma unroll
        for (int j = 0; j < 2; ++j)
            #pragma unroll
            for (int q = 0; q < 4; ++q) acc[i][j][q] = 0.0f;

    stageA128(aP, BND, As[0], w, l);
    stageA128(bP, BND, Bs[0], w, l);

    const int NT = 1024 / 64;   // 16
    for (int t = 0; t < NT; ++t){
        const int cur = t & 1;
        if (t + 1 < NT){
            stageA128(aP + (t+1)*64, BND, As[cur^1], w, l);
            stageA128(bP + (t+1)*64, BND, Bs[cur^1], w, l);
            waitvm4();
        } else {
            waitvm0();
        }
        __builtin_amdgcn_s_barrier();
        bf16x8 af[4][2], bf[2][2];
        #pragma unroll
        for (int h = 0; h < 2; ++h){
            const int cs = ((h*4 + lq) ^ (lm & 7)) * 8;
            #pragma unroll
            for (int i = 0; i < 4; ++i)
                af[i][h] = *reinterpret_cast<const bf16x8*>(&As[cur][(wr + i*16 + lm)*64 + cs]);
            #pragma unroll
            for (int j = 0; j < 2; ++j)
                bf[j][h] = *reinterpret_cast<const bf16x8*>(&Bs[cur][(wc + j*16 + lm)*64 + cs]);
        }
        #pragma unroll
        for (int h = 0; h < 2; ++h)
            #pragma unroll
            for (int i = 0; i < 4; ++i)
                #pragma unroll
                for (int j = 0; j < 2; ++j)
                    acc[i][j] = __builtin_amdgcn_mfma_f32_16x16x32_bf16(af[i][h], bf[j][h], acc[i][j], 0, 0, 0);
        __builtin_amdgcn_s_barrier();
    }

    // C rows = m, cols = dp (lane-contiguous -> coalesced atomics)
    #pragma unroll
    for (int i = 0; i < 4; ++i){
        #pragma unroll
        for (int q = 0; q < 4; ++q){
            int m = m0 + wr + i*16 + lq*4 + q;
            float* rowp = kvp + ((size_t)b*512 + m) * 1024;
            #pragma unroll
            for (int j = 0; j < 2; ++j){
                int dp = dp0 + wc + j*16 + lm;
                atomicAdd(rowp + dp, acc[i][j][q]);
            }
        }
    }
}

// ---------- ksum[b][dp] = sum_n Ktsc[dp, b*NN+n] ----------
__global__ __launch_bounds__(256) void k_ksum(
    const unsigned short* __restrict__ Ktsc,
    float* __restrict__ ksum)
{
    int b = blockIdx.y;
    int dp = blockIdx.x * 4 + (threadIdx.x >> 6);
    int l = threadIdx.x & 63;
    const unsigned short* row = Ktsc + (size_t)dp * BND + b * NN;
    float ss = 0.f;
    for (int c0 = 0; c0 < NN; c0 += 512){
        float f[8];
        unpack8(*reinterpret_cast<const uint4*>(row + c0 + l*8), f);
        #pragma unroll
        for (int u = 0; u < 8; ++u) ss += f[u];
    }
    #pragma unroll
    for (int off = 32; off; off >>= 1) ss += __shfl_xor(ss, off);
    if (l == 0) ksum[b*1024 + dp] = ss;
}

// ---------- z[row] = 1/max(Q2[row,:].ksum[b,:], 1e-6) ----------
__global__ __launch_bounds__(256) void k_z(
    const unsigned short* __restrict__ Q2,
    const float* __restrict__ ksum,
    float* __restrict__ zden)
{
    int row  = blockIdx.x * 4 + (threadIdx.x >> 6);
    int lane = threadIdx.x & 63;
    int b = row >> 12;
    const unsigned short* qp = Q2 + (size_t)row * 1024 + lane * 16;
    float qf[16];
    unpack8(*reinterpret_cast<const uint4*>(qp), qf);
    unpack8(*reinterpret_cast<const uint4*>(qp + 8), qf + 8);
    const float* ks = ksum + (size_t)b*1024 + lane*16;
    float ps = 0.f;
    #pragma unroll
    for (int u = 0; u < 16; ++u) ps = fmaf(qf[u], ks[u], ps);
    #pragma unroll
    for (int off = 32; off; off >>= 1) ps += __shfl_xor(ps, off);
    if (lane == 0) zden[row] = 1.0f / fmaxf(ps, 1e-6f);
}

// ---------- out[n][m] = z * sum_dp Q2[n,dp]*kvb[b,m,dp]; 128x64; 8-wave; counted vmcnt ----------
__global__ __launch_bounds__(512) void k_out(
    const unsigned short* __restrict__ Q2,
    const unsigned short* __restrict__ kvb,
    const float* __restrict__ zden,
    float* __restrict__ Out)
{
    __shared__ __align__(16) unsigned short As[2][128*64];
    __shared__ __align__(16) unsigned short Bs[2][64*64];

    const int tid = threadIdx.x;
    const int r0 = blockIdx.x * 128;
    const int m0 = blockIdx.y * 64;
    const int b  = r0 >> 12;
    const int w  = tid >> 6, l = tid & 63;
    const int wr = (w >> 2) * 64, wc = (w & 3) * 16;
    const int lm = l & 15, lq = l >> 4;

    const unsigned short* aP = Q2 + (size_t)r0 * 1024;
    const unsigned short* bP = kvb + ((size_t)b*512 + m0) * 1024;

    f32x4 acc[4];
    #pragma unroll
    for (int i = 0; i < 4; ++i)
        #pragma unroll
        for (int q = 0; q < 4; ++q) acc[i][q] = 0.0f;

    stageA128(aP, 1024, As[0], w, l);
    stageB64 (bP, 1024, Bs[0], w, l);

    const int NT = 1024 / 64;   // 16
    for (int t = 0; t < NT; ++t){
        const int cur = t & 1;
        if (t + 1 < NT){
            stageA128(aP + (t+1)*64, 1024, As[cur^1], w, l);
            stageB64 (bP + (t+1)*64, 1024, Bs[cur^1], w, l);
            waitvm3();
        } else {
            waitvm0();
        }
        __builtin_amdgcn_s_barrier();
        bf16x8 af[4][2], bf[2];
        #pragma unroll
        for (int h = 0; h < 2; ++h){
            const int cs = ((h*4 + lq) ^ (lm & 7)) * 8;
            #pragma unroll
            for (int i = 0; i < 4; ++i)
                af[i][h] = *reinterpret_cast<const bf16x8*>(&As[cur][(wr + i*16 + lm)*64 + cs]);
            bf[h] = *reinterpret_cast<const bf16x8*>(&Bs[cur][(wc + lm)*64 + cs]);
        }
        #pragma unroll
        for (int h = 0; h < 2; ++h)
            #pragma unroll
            for (int i = 0; i < 4; ++i)
                acc[i] = __builtin_amdgcn_mfma_f32_16x16x32_bf16(af[i][h], bf[h], acc[i], 0, 0, 0);
        __builtin_amdgcn_s_barrier();
    }

    #pragma unroll
    for (int i = 0; i < 4; ++i){
        #pragma unroll
        for (int q = 0; q < 4; ++q){
            int grow = r0 + wr + i*16 + lq*4 + q;
            int n = grow & (NN - 1);
            float z  = zden[grow];
            int hh = n >> 9;
            int ttb = (n & 511) * 8;
            int m = m0 + wc + lm;
            int tt = ttb + (m >> 6);
            Out[((size_t)b*NN + tt) * DD + hh*64 + (m & 63)] = acc[i][q] * z;
        }
    }
}

extern "C" void kernel_launch(void* const* d_in, const int* in_sizes, int n_in,
                              void* d_out, int out_size, void* d_ws, size_t ws_size,
                              hipStream_t stream)
{
    const float* X  = (const float*)d_in[0];
    const float* Wq = (const float*)d_in[1];
    const float* Wk = (const float*)d_in[2];
    const float* Wv = (const float*)d_in[3];
    float* Out = (float*)d_out;

    char* p = (char*)d_ws;
    float* sincos = (float*)p; p += (size_t)2*NN*sizeof(float);
    float* kvp    = (float*)p; p += (size_t)BB*512*1024*sizeof(float);   // 8 MB
    float* ksum   = (float*)p; p += (size_t)BB*1024*sizeof(float);
    float* zden   = (float*)p; p += (size_t)BND*sizeof(float);
    unsigned short* Xb   = (unsigned short*)p; p += (size_t)BND*DD*2;        // 16 MB
    unsigned short* Wqb  = (unsigned short*)p; p += (size_t)DD*DD*2;
    unsigned short* Wkb  = (unsigned short*)p; p += (size_t)DD*DD*2;
    unsigned short* Wvb  = (unsigned short*)p; p += (size_t)DD*DD*2;
    unsigned short* Q2   = (unsigned short*)p; p += (size_t)BND*1024*2;      // 32 MB
    unsigned short* Ktsc = (unsigned short*)p; p += (size_t)1024*BND*2;      // 32 MB
    unsigned short* Vt   = (unsigned short*)p; p += (size_t)512*BND*2;       // 16 MB
    unsigned short* kvb  = (unsigned short*)p; p += (size_t)BB*512*1024*2;   // 4 MB

    hipMemsetAsync(kvp, 0, (size_t)BB*512*1024*sizeof(float), stream);

    k_sincos<<<dim3(16), dim3(256), 0, stream>>>(sincos);
    k_cvt   <<<dim3(4096), dim3(256), 0, stream>>>(X,  Xb,  BND*DD/8);
    k_cvt   <<<dim3(128),  dim3(256), 0, stream>>>(Wq, Wqb, DD*DD/8);
    k_cvt   <<<dim3(128),  dim3(256), 0, stream>>>(Wk, Wkb, DD*DD/8);
    k_cvt   <<<dim3(128),  dim3(256), 0, stream>>>(Wv, Wvb, DD*DD/8);
    k_qkv   <<<dim3(BND/128, DD/128, 3), dim3(512), 0, stream>>>(Xb, Wqb, Wkb, Wvb, sincos, Q2, Ktsc, Vt);
    k_kv    <<<dim3(4, 8, BB*4), dim3(512), 0, stream>>>(Vt, Ktsc, kvp);
    k_ksum  <<<dim3(256, 4), dim3(256), 0, stream>>>(Ktsc, ksum);
    k_z     <<<dim3(BND/4), dim3(256), 0, stream>>>(Q2, ksum, zden);
    k_cvt   <<<dim3(1024), dim3(256), 0, stream>>>(kvp, kvb, BB*512*1024/8);
    k_out   <<<dim3(BND/128, DD/64), dim3(512), 0, stream>>>(Q2, kvb, zden, Out);
}

// Round 12
// 155.799 us; speedup vs baseline: 1.2787x; 1.0632x over previous
//
#include <hip/hip_runtime.h>
#include <hip/hip_bf16.h>

#define BB 4
#define NN 4096
#define DD 512
#define BND (BB*NN)   // 16384

typedef __attribute__((ext_vector_type(8))) short bf16x8;
typedef __attribute__((ext_vector_type(4))) float f32x4;

// ---------- bf16 helpers ----------
__device__ __forceinline__ float b2f(unsigned int u){
    union { unsigned int u; float f; } c; c.u = u << 16; return c.f;
}
__device__ __forceinline__ unsigned short f2b(float f){
    union { float f; unsigned int u; } c; c.f = f;
    unsigned int r = c.u + 0x7fffu + ((c.u >> 16) & 1u);   // RNE
    return (unsigned short)(r >> 16);
}
__device__ __forceinline__ unsigned int pack2(float lo, float hi){
    __hip_bfloat162 h = __float22bfloat162_rn(make_float2(lo, hi));
    return *reinterpret_cast<unsigned int*>(&h);
}
__device__ __forceinline__ void unpack8(uint4 v, float* o){
    o[0]=b2f(v.x & 0xffffu); o[1]=b2f(v.x >> 16);
    o[2]=b2f(v.y & 0xffffu); o[3]=b2f(v.y >> 16);
    o[4]=b2f(v.z & 0xffffu); o[5]=b2f(v.z >> 16);
    o[6]=b2f(v.w & 0xffffu); o[7]=b2f(v.w >> 16);
}

// async global->LDS, 16B/lane; lds dest is wave-uniform base + lane*16
__device__ __forceinline__ void gload16(const void* g, void* l){
    __builtin_amdgcn_global_load_lds(
        (const __attribute__((address_space(1))) unsigned int*)g,
        (__attribute__((address_space(3))) unsigned int*)l,
        16, 0, 0);
}

// counted vmcnt waits (T4)
__device__ __forceinline__ void waitvm8(){ asm volatile("s_waitcnt vmcnt(8)" ::: "memory"); }
__device__ __forceinline__ void waitvm4(){ asm volatile("s_waitcnt vmcnt(4)" ::: "memory"); }
__device__ __forceinline__ void waitvm0(){ asm volatile("s_waitcnt vmcnt(0)" ::: "memory"); }

// ---- XOR-swizzled staging, 8-wave (512 threads) ----
// LDS rows of 64 bf16 (8 chunks x 16B). Phys chunk c of row r holds logical chunk c^(r&7).
__device__ __forceinline__ void stageA128(const unsigned short* g, size_t gstride,
                                          unsigned short* lds, int w, int l){
    const int rr = l >> 3;                      // 0..7 == row&7
    const int sc = ((l & 7) ^ rr) * 8;          // swizzled source chunk
    const unsigned short* src = g + (size_t)(w*16 + rr) * gstride + sc;
    unsigned short* dst = lds + w*16*64;
    gload16(src,                       dst);
    gload16(src + (size_t)8*gstride,   dst + 8*64);
}

// ---------- sin/cos table ----------
__global__ void k_sincos(float* __restrict__ sc){
    int t = blockIdx.x * 256 + threadIdx.x;
    if (t < NN){
        float idx = 1.5707963267948966f * ((float)(t + 1) / (float)NN);
        sc[t]      = sinf(idx);
        sc[NN + t] = cosf(idx);
    }
}

// ---------- fp32 -> bf16 bulk convert ----------
__global__ void k_cvt(const float* __restrict__ in, unsigned short* __restrict__ out, int n8){
    int t = blockIdx.x * 256 + threadIdx.x;
    if (t < n8){
        float4 a = reinterpret_cast<const float4*>(in)[t*2];
        float4 b = reinterpret_cast<const float4*>(in)[t*2+1];
        uint4 st;
        st.x = pack2(a.x, a.y); st.y = pack2(a.z, a.w);
        st.z = pack2(b.x, b.y); st.w = pack2(b.z, b.w);
        reinterpret_cast<uint4*>(out)[t] = st;
    }
}

// ---------- FUSED q,k,v projections: one A staging, three B tiles ----------
// Q2=[sin*q|cos*q] row-major [BND][1024]; Ktsc=[sin*k;cos*k] transposed [1024][BND];
// Vt transposed [512][BND]. 8 waves, 128x128 tile, BK=64, counted vmcnt.
__global__ __launch_bounds__(512) void k_qkv(
    const unsigned short* __restrict__ Xb,
    const unsigned short* __restrict__ Wqb,
    const unsigned short* __restrict__ Wkb,
    const unsigned short* __restrict__ Wvb,
    const float* __restrict__ sc,
    unsigned short* __restrict__ Q2,
    unsigned short* __restrict__ Ktsc,
    unsigned short* __restrict__ Vt)
{
    __shared__ __align__(16) unsigned short As[2][128*64];
    __shared__ __align__(16) unsigned short Bq[2][128*64];
    __shared__ __align__(16) unsigned short Bk[2][128*64];
    __shared__ __align__(16) unsigned short Bv[2][128*64];

    const int tid = threadIdx.x;
    const int r0 = blockIdx.x * 128;
    const int c0 = blockIdx.y * 128;
    const int w  = tid >> 6, l = tid & 63;
    const int wr = (w >> 2) * 64;          // 2 row groups
    const int wc = (w & 3) * 32;           // 4 col groups
    const int lm = l & 15, lq = l >> 4;

    const unsigned short* aP = Xb  + (size_t)r0 * DD;
    const unsigned short* qP = Wqb + (size_t)c0 * DD;
    const unsigned short* kP = Wkb + (size_t)c0 * DD;
    const unsigned short* vP = Wvb + (size_t)c0 * DD;

    f32x4 aq[4][2], ak[4][2], av[4][2];
    #pragma unroll
    for (int i = 0; i < 4; ++i)
        #pragma unroll
        for (int j = 0; j < 2; ++j)
            #pragma unroll
            for (int q = 0; q < 4; ++q){ aq[i][j][q]=0.f; ak[i][j][q]=0.f; av[i][j][q]=0.f; }

    stageA128(aP, DD, As[0], w, l);
    stageA128(qP, DD, Bq[0], w, l);
    stageA128(kP, DD, Bk[0], w, l);
    stageA128(vP, DD, Bv[0], w, l);

    const int NT = DD / 64;     // 8
    for (int t = 0; t < NT; ++t){
        const int cur = t & 1;
        if (t + 1 < NT){
            stageA128(aP + (t+1)*64, DD, As[cur^1], w, l);
            stageA128(qP + (t+1)*64, DD, Bq[cur^1], w, l);
            stageA128(kP + (t+1)*64, DD, Bk[cur^1], w, l);
            stageA128(vP + (t+1)*64, DD, Bv[cur^1], w, l);
            waitvm8();                      // stage(t) landed; stage(t+1) in flight
        } else {
            waitvm0();
        }
        __builtin_amdgcn_s_barrier();
        bf16x8 af[4][2];
        #pragma unroll
        for (int h = 0; h < 2; ++h){
            const int cs = ((h*4 + lq) ^ (lm & 7)) * 8;
            #pragma unroll
            for (int i = 0; i < 4; ++i)
                af[i][h] = *reinterpret_cast<const bf16x8*>(&As[cur][(wr + i*16 + lm)*64 + cs]);
        }
        // q
        {
            bf16x8 bf[2][2];
            #pragma unroll
            for (int h = 0; h < 2; ++h){
                const int cs = ((h*4 + lq) ^ (lm & 7)) * 8;
                #pragma unroll
                for (int j = 0; j < 2; ++j)
                    bf[j][h] = *reinterpret_cast<const bf16x8*>(&Bq[cur][(wc + j*16 + lm)*64 + cs]);
            }
            #pragma unroll
            for (int h = 0; h < 2; ++h)
                #pragma unroll
                for (int i = 0; i < 4; ++i)
                    #pragma unroll
                    for (int j = 0; j < 2; ++j)
                        aq[i][j] = __builtin_amdgcn_mfma_f32_16x16x32_bf16(af[i][h], bf[j][h], aq[i][j], 0, 0, 0);
        }
        // k
        {
            bf16x8 bf[2][2];
            #pragma unroll
            for (int h = 0; h < 2; ++h){
                const int cs = ((h*4 + lq) ^ (lm & 7)) * 8;
                #pragma unroll
                for (int j = 0; j < 2; ++j)
                    bf[j][h] = *reinterpret_cast<const bf16x8*>(&Bk[cur][(wc + j*16 + lm)*64 + cs]);
            }
            #pragma unroll
            for (int h = 0; h < 2; ++h)
                #pragma unroll
                for (int i = 0; i < 4; ++i)
                    #pragma unroll
                    for (int j = 0; j < 2; ++j)
                        ak[i][j] = __builtin_amdgcn_mfma_f32_16x16x32_bf16(af[i][h], bf[j][h], ak[i][j], 0, 0, 0);
        }
        // v
        {
            bf16x8 bf[2][2];
            #pragma unroll
            for (int h = 0; h < 2; ++h){
                const int cs = ((h*4 + lq) ^ (lm & 7)) * 8;
                #pragma unroll
                for (int j = 0; j < 2; ++j)
                    bf[j][h] = *reinterpret_cast<const bf16x8*>(&Bv[cur][(wc + j*16 + lm)*64 + cs]);
            }
            #pragma unroll
            for (int h = 0; h < 2; ++h)
                #pragma unroll
                for (int i = 0; i < 4; ++i)
                    #pragma unroll
                    for (int j = 0; j < 2; ++j)
                        av[i][j] = __builtin_amdgcn_mfma_f32_16x16x32_bf16(af[i][h], bf[j][h], av[i][j], 0, 0, 0);
        }
        __builtin_amdgcn_s_barrier();
    }

    // epilogue Q: row-major Q2 with relu + sin/cos duplication
    #pragma unroll
    for (int i = 0; i < 4; ++i){
        #pragma unroll
        for (int q = 0; q < 4; ++q){
            int row = r0 + wr + i*16 + lq*4 + q;
            int n = row & (NN - 1);
            float sn = sc[n], cn = sc[NN + n];
            size_t base = (size_t)row * 1024 + c0 + wc + lm;
            #pragma unroll
            for (int j = 0; j < 2; ++j){
                float v = fmaxf(aq[i][j][q], 0.0f);
                Q2[base + j*16]       = f2b(sn * v);
                Q2[base + 512 + j*16] = f2b(cn * v);
            }
        }
    }
    // epilogue K: transposed, pre-scaled
    #pragma unroll
    for (int i = 0; i < 4; ++i){
        int rb = r0 + wr + i*16 + lq*4;
        int n  = rb & (NN - 1);
        float4 s4 = *reinterpret_cast<const float4*>(sc + n);
        float4 c4 = *reinterpret_cast<const float4*>(sc + NN + n);
        #pragma unroll
        for (int j = 0; j < 2; ++j){
            int d = c0 + wc + j*16 + lm;
            float v0 = fmaxf(ak[i][j][0], 0.f), v1 = fmaxf(ak[i][j][1], 0.f);
            float v2 = fmaxf(ak[i][j][2], 0.f), v3 = fmaxf(ak[i][j][3], 0.f);
            uint2 stS, stC;
            stS.x = pack2(v0*s4.x, v1*s4.y); stS.y = pack2(v2*s4.z, v3*s4.w);
            stC.x = pack2(v0*c4.x, v1*c4.y); stC.y = pack2(v2*c4.z, v3*c4.w);
            *reinterpret_cast<uint2*>(Ktsc + (size_t)d * BND + rb)         = stS;
            *reinterpret_cast<uint2*>(Ktsc + (size_t)(512 + d) * BND + rb) = stC;
        }
    }
    // epilogue V: transposed
    #pragma unroll
    for (int i = 0; i < 4; ++i){
        int rb = r0 + wr + i*16 + lq*4;
        #pragma unroll
        for (int j = 0; j < 2; ++j){
            int d = c0 + wc + j*16 + lm;
            uint2 st;
            st.x = pack2(av[i][j][0], av[i][j][1]);
            st.y = pack2(av[i][j][2], av[i][j][3]);
            *reinterpret_cast<uint2*>(Vt + (size_t)d * BND + rb) = st;
        }
    }
}

// ---------- kvp[b][m][dp] += sum_n Vt[m,n]*Ktsc[dp,n]; split-4; 8-wave; counted vmcnt ----------
__global__ __launch_bounds__(512) void k_kv(
    const unsigned short* __restrict__ Vt,
    const unsigned short* __restrict__ Ktsc,
    float* __restrict__ kvp)
{
    __shared__ __align__(16) unsigned short As[2][128*64];
    __shared__ __align__(16) unsigned short Bs[2][128*64];

    const int tid = threadIdx.x;
    const int m0  = blockIdx.x * 128;
    const int b   = blockIdx.z >> 2;
    const int sp  = blockIdx.z & 3;
    const int dp0 = ((blockIdx.y + sp) & 7) * 128;   // stagger across sp
    const int cb  = b * NN + sp * 1024;
    const int w  = tid >> 6, l = tid & 63;
    const int wr = (w >> 2) * 64, wc = (w & 3) * 32;
    const int lm = l & 15, lq = l >> 4;

    const unsigned short* aP = Vt   + (size_t)m0  * BND + cb;
    const unsigned short* bP = Ktsc + (size_t)dp0 * BND + cb;

    f32x4 acc[4][2];
    #pragma unroll
    for (int i = 0; i < 4; ++i)
        #pragma unroll
        for (int j = 0; j < 2; ++j)
            #pragma unroll
            for (int q = 0; q < 4; ++q) acc[i][j][q] = 0.0f;

    stageA128(aP, BND, As[0], w, l);
    stageA128(bP, BND, Bs[0], w, l);

    const int NT = 1024 / 64;   // 16
    for (int t = 0; t < NT; ++t){
        const int cur = t & 1;
        if (t + 1 < NT){
            stageA128(aP + (t+1)*64, BND, As[cur^1], w, l);
            stageA128(bP + (t+1)*64, BND, Bs[cur^1], w, l);
            waitvm4();
        } else {
            waitvm0();
        }
        __builtin_amdgcn_s_barrier();
        bf16x8 af[4][2], bf[2][2];
        #pragma unroll
        for (int h = 0; h < 2; ++h){
            const int cs = ((h*4 + lq) ^ (lm & 7)) * 8;
            #pragma unroll
            for (int i = 0; i < 4; ++i)
                af[i][h] = *reinterpret_cast<const bf16x8*>(&As[cur][(wr + i*16 + lm)*64 + cs]);
            #pragma unroll
            for (int j = 0; j < 2; ++j)
                bf[j][h] = *reinterpret_cast<const bf16x8*>(&Bs[cur][(wc + j*16 + lm)*64 + cs]);
        }
        #pragma unroll
        for (int h = 0; h < 2; ++h)
            #pragma unroll
            for (int i = 0; i < 4; ++i)
                #pragma unroll
                for (int j = 0; j < 2; ++j)
                    acc[i][j] = __builtin_amdgcn_mfma_f32_16x16x32_bf16(af[i][h], bf[j][h], acc[i][j], 0, 0, 0);
        __builtin_amdgcn_s_barrier();
    }

    #pragma unroll
    for (int i = 0; i < 4; ++i){
        #pragma unroll
        for (int q = 0; q < 4; ++q){
            int m = m0 + wr + i*16 + lq*4 + q;
            float* rowp = kvp + ((size_t)b*512 + m) * 1024;
            #pragma unroll
            for (int j = 0; j < 2; ++j){
                int dp = dp0 + wc + j*16 + lm;
                atomicAdd(rowp + dp, acc[i][j][q]);
            }
        }
    }
}

// ---------- ksum[b][dp] = sum_n Ktsc[dp, b*NN+n] ----------
__global__ __launch_bounds__(256) void k_ksum(
    const unsigned short* __restrict__ Ktsc,
    float* __restrict__ ksum)
{
    int b = blockIdx.y;
    int dp = blockIdx.x * 4 + (threadIdx.x >> 6);
    int l = threadIdx.x & 63;
    const unsigned short* row = Ktsc + (size_t)dp * BND + b * NN;
    float ss = 0.f;
    for (int c0 = 0; c0 < NN; c0 += 512){
        float f[8];
        unpack8(*reinterpret_cast<const uint4*>(row + c0 + l*8), f);
        #pragma unroll
        for (int u = 0; u < 8; ++u) ss += f[u];
    }
    #pragma unroll
    for (int off = 32; off; off >>= 1) ss += __shfl_xor(ss, off);
    if (l == 0) ksum[b*1024 + dp] = ss;
}

// ---------- z[row] = 1/max(Q2[row,:].ksum[b,:], 1e-6) ----------
__global__ __launch_bounds__(256) void k_z(
    const unsigned short* __restrict__ Q2,
    const float* __restrict__ ksum,
    float* __restrict__ zden)
{
    int row  = blockIdx.x * 4 + (threadIdx.x >> 6);
    int lane = threadIdx.x & 63;
    int b = row >> 12;
    const unsigned short* qp = Q2 + (size_t)row * 1024 + lane * 16;
    float qf[16];
    unpack8(*reinterpret_cast<const uint4*>(qp), qf);
    unpack8(*reinterpret_cast<const uint4*>(qp + 8), qf + 8);
    const float* ks = ksum + (size_t)b*1024 + lane*16;
    float ps = 0.f;
    #pragma unroll
    for (int u = 0; u < 16; ++u) ps = fmaf(qf[u], ks[u], ps);
    #pragma unroll
    for (int off = 32; off; off >>= 1) ps += __shfl_xor(ps, off);
    if (lane == 0) zden[row] = 1.0f / fmaxf(ps, 1e-6f);
}

// ---------- out[n][m] = z * sum_dp Q2[n,dp]*kvb[b,m,dp]; 128x128 tiles; 8-wave ----------
__global__ __launch_bounds__(512) void k_out(
    const unsigned short* __restrict__ Q2,
    const unsigned short* __restrict__ kvb,
    const float* __restrict__ zden,
    float* __restrict__ Out)
{
    __shared__ __align__(16) unsigned short As[2][128*64];
    __shared__ __align__(16) unsigned short Bs[2][128*64];

    const int tid = threadIdx.x;
    const int r0 = blockIdx.x * 128;
    const int m0 = blockIdx.y * 128;
    const int b  = r0 >> 12;
    const int w  = tid >> 6, l = tid & 63;
    const int wr = (w >> 2) * 64, wc = (w & 3) * 32;
    const int lm = l & 15, lq = l >> 4;

    const unsigned short* aP = Q2 + (size_t)r0 * 1024;
    const unsigned short* bP = kvb + ((size_t)b*512 + m0) * 1024;

    f32x4 acc[4][2];
    #pragma unroll
    for (int i = 0; i < 4; ++i)
        #pragma unroll
        for (int j = 0; j < 2; ++j)
            #pragma unroll
            for (int q = 0; q < 4; ++q) acc[i][j][q] = 0.0f;

    stageA128(aP, 1024, As[0], w, l);
    stageA128(bP, 1024, Bs[0], w, l);

    const int NT = 1024 / 64;   // 16
    for (int t = 0; t < NT; ++t){
        const int cur = t & 1;
        if (t + 1 < NT){
            stageA128(aP + (t+1)*64, 1024, As[cur^1], w, l);
            stageA128(bP + (t+1)*64, 1024, Bs[cur^1], w, l);
            waitvm4();
        } else {
            waitvm0();
        }
        __builtin_amdgcn_s_barrier();
        bf16x8 af[4][2], bf[2][2];
        #pragma unroll
        for (int h = 0; h < 2; ++h){
            const int cs = ((h*4 + lq) ^ (lm & 7)) * 8;
            #pragma unroll
            for (int i = 0; i < 4; ++i)
                af[i][h] = *reinterpret_cast<const bf16x8*>(&As[cur][(wr + i*16 + lm)*64 + cs]);
            #pragma unroll
            for (int j = 0; j < 2; ++j)
                bf[j][h] = *reinterpret_cast<const bf16x8*>(&Bs[cur][(wc + j*16 + lm)*64 + cs]);
        }
        #pragma unroll
        for (int h = 0; h < 2; ++h)
            #pragma unroll
            for (int i = 0; i < 4; ++i)
                #pragma unroll
                for (int j = 0; j < 2; ++j)
                    acc[i][j] = __builtin_amdgcn_mfma_f32_16x16x32_bf16(af[i][h], bf[j][h], acc[i][j], 0, 0, 0);
        __builtin_amdgcn_s_barrier();
    }

    #pragma unroll
    for (int i = 0; i < 4; ++i){
        #pragma unroll
        for (int q = 0; q < 4; ++q){
            int grow = r0 + wr + i*16 + lq*4 + q;
            int n = grow & (NN - 1);
            float z  = zden[grow];
            int hh = n >> 9;
            int ttb = (n & 511) * 8;
            #pragma unroll
            for (int j = 0; j < 2; ++j){
                int m = m0 + wc + j*16 + lm;
                int tt = ttb + (m >> 6);
                Out[((size_t)b*NN + tt) * DD + hh*64 + (m & 63)] = acc[i][j][q] * z;
            }
        }
    }
}

extern "C" void kernel_launch(void* const* d_in, const int* in_sizes, int n_in,
                              void* d_out, int out_size, void* d_ws, size_t ws_size,
                              hipStream_t stream)
{
    const float* X  = (const float*)d_in[0];
    const float* Wq = (const float*)d_in[1];
    const float* Wk = (const float*)d_in[2];
    const float* Wv = (const float*)d_in[3];
    float* Out = (float*)d_out;

    char* p = (char*)d_ws;
    float* sincos = (float*)p; p += (size_t)2*NN*sizeof(float);
    float* kvp    = (float*)p; p += (size_t)BB*512*1024*sizeof(float);   // 8 MB
    float* ksum   = (float*)p; p += (size_t)BB*1024*sizeof(float);
    float* zden   = (float*)p; p += (size_t)BND*sizeof(float);
    unsigned short* Xb   = (unsigned short*)p; p += (size_t)BND*DD*2;        // 16 MB
    unsigned short* Wqb  = (unsigned short*)p; p += (size_t)DD*DD*2;
    unsigned short* Wkb  = (unsigned short*)p; p += (size_t)DD*DD*2;
    unsigned short* Wvb  = (unsigned short*)p; p += (size_t)DD*DD*2;
    unsigned short* Q2   = (unsigned short*)p; p += (size_t)BND*1024*2;      // 32 MB
    unsigned short* Ktsc = (unsigned short*)p; p += (size_t)1024*BND*2;      // 32 MB
    unsigned short* Vt   = (unsigned short*)p; p += (size_t)512*BND*2;       // 16 MB
    unsigned short* kvb  = (unsigned short*)p; p += (size_t)BB*512*1024*2;   // 4 MB

    hipMemsetAsync(kvp, 0, (size_t)BB*512*1024*sizeof(float), stream);

    k_sincos<<<dim3(16), dim3(256), 0, stream>>>(sincos);
    k_cvt   <<<dim3(4096), dim3(256), 0, stream>>>(X,  Xb,  BND*DD/8);
    k_cvt   <<<dim3(128),  dim3(256), 0, stream>>>(Wq, Wqb, DD*DD/8);
    k_cvt   <<<dim3(128),  dim3(256), 0, stream>>>(Wk, Wkb, DD*DD/8);
    k_cvt   <<<dim3(128),  dim3(256), 0, stream>>>(Wv, Wvb, DD*DD/8);
    k_qkv   <<<dim3(BND/128, DD/128), dim3(512), 0, stream>>>(Xb, Wqb, Wkb, Wvb, sincos, Q2, Ktsc, Vt);
    k_kv    <<<dim3(4, 8, BB*4), dim3(512), 0, stream>>>(Vt, Ktsc, kvp);
    k_ksum  <<<dim3(256, 4), dim3(256), 0, stream>>>(Ktsc, ksum);
    k_z     <<<dim3(BND/4), dim3(256), 0, stream>>>(Q2, ksum, zden);
    k_cvt   <<<dim3(1024), dim3(256), 0, stream>>>(kvp, kvb, BB*512*1024/8);
    k_out   <<<dim3(BND/128, DD/128), dim3(512), 0, stream>>>(Q2, kvb, zden, Out);
}

// Round 13
// 137.225 us; speedup vs baseline: 1.4518x; 1.1353x over previous
//
#include <hip/hip_runtime.h>
#include <hip/hip_bf16.h>

#define BB 4
#define NN 4096
#define DD 512
#define BND (BB*NN)   // 16384

typedef __attribute__((ext_vector_type(8))) short bf16x8;
typedef __attribute__((ext_vector_type(4))) float f32x4;

// ---------- bf16 helpers ----------
__device__ __forceinline__ float b2f(unsigned int u){
    union { unsigned int u; float f; } c; c.u = u << 16; return c.f;
}
__device__ __forceinline__ unsigned short f2b(float f){
    union { float f; unsigned int u; } c; c.f = f;
    unsigned int r = c.u + 0x7fffu + ((c.u >> 16) & 1u);   // RNE
    return (unsigned short)(r >> 16);
}
__device__ __forceinline__ unsigned int pack2(float lo, float hi){
    __hip_bfloat162 h = __float22bfloat162_rn(make_float2(lo, hi));
    return *reinterpret_cast<unsigned int*>(&h);
}
__device__ __forceinline__ void unpack8(uint4 v, float* o){
    o[0]=b2f(v.x & 0xffffu); o[1]=b2f(v.x >> 16);
    o[2]=b2f(v.y & 0xffffu); o[3]=b2f(v.y >> 16);
    o[4]=b2f(v.z & 0xffffu); o[5]=b2f(v.z >> 16);
    o[6]=b2f(v.w & 0xffffu); o[7]=b2f(v.w >> 16);
}

// async global->LDS, 16B/lane; lds dest is wave-uniform base + lane*16
__device__ __forceinline__ void gload16(const void* g, void* l){
    __builtin_amdgcn_global_load_lds(
        (const __attribute__((address_space(1))) unsigned int*)g,
        (__attribute__((address_space(3))) unsigned int*)l,
        16, 0, 0);
}

// counted vmcnt waits (T4)
__device__ __forceinline__ void waitvm4(){ asm volatile("s_waitcnt vmcnt(4)" ::: "memory"); }
__device__ __forceinline__ void waitvm0(){ asm volatile("s_waitcnt vmcnt(0)" ::: "memory"); }

// ---- XOR-swizzled staging, 8-wave (512 threads) ----
// BK=64 tiles: LDS rows of 64 bf16 (8 chunks x 16B); phys chunk c of row r = logical c^(r&7).
__device__ __forceinline__ void stageA128(const unsigned short* g, size_t gstride,
                                          unsigned short* lds, int w, int l){
    const int rr = l >> 3;
    const int sc = ((l & 7) ^ rr) * 8;
    const unsigned short* src = g + (size_t)(w*16 + rr) * gstride + sc;
    unsigned short* dst = lds + w*16*64;
    gload16(src,                       dst);
    gload16(src + (size_t)8*gstride,   dst + 8*64);
}
// BK=32 tiles: rows of 32 bf16 (4 chunks x 16B); phys chunk c of row r = logical c^(r&3).
// 128 rows, 512 threads -> 1 gload each.
__device__ __forceinline__ void stage32(const unsigned short* g, size_t gstride,
                                        unsigned short* lds, int w, int l){
    const int row = l >> 2;                      // 0..15 within wave's 16 rows
    const int sc  = ((l & 3) ^ (row & 3)) * 8;   // swizzled source chunk
    gload16(g + (size_t)(w*16 + row) * gstride + sc, lds + w*16*32);
}

// ---------- sin/cos table ----------
__global__ void k_sincos(float* __restrict__ sc){
    int t = blockIdx.x * 256 + threadIdx.x;
    if (t < NN){
        float idx = 1.5707963267948966f * ((float)(t + 1) / (float)NN);
        sc[t]      = sinf(idx);
        sc[NN + t] = cosf(idx);
    }
}

// ---------- fp32 -> bf16 bulk convert ----------
__global__ void k_cvt(const float* __restrict__ in, unsigned short* __restrict__ out, int n8){
    int t = blockIdx.x * 256 + threadIdx.x;
    if (t < n8){
        float4 a = reinterpret_cast<const float4*>(in)[t*2];
        float4 b = reinterpret_cast<const float4*>(in)[t*2+1];
        uint4 st;
        st.x = pack2(a.x, a.y); st.y = pack2(a.z, a.w);
        st.z = pack2(b.x, b.y); st.w = pack2(b.z, b.w);
        reinterpret_cast<uint4*>(out)[t] = st;
    }
}

// ---------- FUSED q,k,v projections, BK=32, 2 blocks/CU ----------
__global__ __launch_bounds__(512) void k_qkv(
    const unsigned short* __restrict__ Xb,
    const unsigned short* __restrict__ Wqb,
    const unsigned short* __restrict__ Wkb,
    const unsigned short* __restrict__ Wvb,
    const float* __restrict__ sc,
    unsigned short* __restrict__ Q2,
    unsigned short* __restrict__ Ktsc,
    unsigned short* __restrict__ Vt)
{
    __shared__ __align__(16) unsigned short As[2][128*32];
    __shared__ __align__(16) unsigned short Bq[2][128*32];
    __shared__ __align__(16) unsigned short Bk[2][128*32];
    __shared__ __align__(16) unsigned short Bv[2][128*32];

    const int tid = threadIdx.x;
    const int r0 = blockIdx.x * 128;
    const int c0 = blockIdx.y * 128;
    const int w  = tid >> 6, l = tid & 63;
    const int wr = (w >> 2) * 64;
    const int wc = (w & 3) * 32;
    const int lm = l & 15, lq = l >> 4;

    const unsigned short* aP = Xb  + (size_t)r0 * DD;
    const unsigned short* qP = Wqb + (size_t)c0 * DD;
    const unsigned short* kP = Wkb + (size_t)c0 * DD;
    const unsigned short* vP = Wvb + (size_t)c0 * DD;

    f32x4 aq[4][2], ak[4][2], av[4][2];
    #pragma unroll
    for (int i = 0; i < 4; ++i)
        #pragma unroll
        for (int j = 0; j < 2; ++j)
            #pragma unroll
            for (int q = 0; q < 4; ++q){ aq[i][j][q]=0.f; ak[i][j][q]=0.f; av[i][j][q]=0.f; }

    stage32(aP, DD, As[0], w, l);
    stage32(qP, DD, Bq[0], w, l);
    stage32(kP, DD, Bk[0], w, l);
    stage32(vP, DD, Bv[0], w, l);

    const int NT = DD / 32;     // 16
    for (int t = 0; t < NT; ++t){
        const int cur = t & 1;
        if (t + 1 < NT){
            stage32(aP + (t+1)*32, DD, As[cur^1], w, l);
            stage32(qP + (t+1)*32, DD, Bq[cur^1], w, l);
            stage32(kP + (t+1)*32, DD, Bk[cur^1], w, l);
            stage32(vP + (t+1)*32, DD, Bv[cur^1], w, l);
            waitvm4();                  // stage(t) landed; stage(t+1) in flight
        } else {
            waitvm0();
        }
        __builtin_amdgcn_s_barrier();
        const int csA = (lq ^ (lm & 3)) * 8;   // logical chunk lq of row (..+lm)
        bf16x8 af[4];
        #pragma unroll
        for (int i = 0; i < 4; ++i)
            af[i] = *reinterpret_cast<const bf16x8*>(&As[cur][(wr + i*16 + lm)*32 + csA]);
        {
            bf16x8 bf[2];
            #pragma unroll
            for (int j = 0; j < 2; ++j)
                bf[j] = *reinterpret_cast<const bf16x8*>(&Bq[cur][(wc + j*16 + lm)*32 + csA]);
            #pragma unroll
            for (int i = 0; i < 4; ++i)
                #pragma unroll
                for (int j = 0; j < 2; ++j)
                    aq[i][j] = __builtin_amdgcn_mfma_f32_16x16x32_bf16(af[i], bf[j], aq[i][j], 0, 0, 0);
        }
        {
            bf16x8 bf[2];
            #pragma unroll
            for (int j = 0; j < 2; ++j)
                bf[j] = *reinterpret_cast<const bf16x8*>(&Bk[cur][(wc + j*16 + lm)*32 + csA]);
            #pragma unroll
            for (int i = 0; i < 4; ++i)
                #pragma unroll
                for (int j = 0; j < 2; ++j)
                    ak[i][j] = __builtin_amdgcn_mfma_f32_16x16x32_bf16(af[i], bf[j], ak[i][j], 0, 0, 0);
        }
        {
            bf16x8 bf[2];
            #pragma unroll
            for (int j = 0; j < 2; ++j)
                bf[j] = *reinterpret_cast<const bf16x8*>(&Bv[cur][(wc + j*16 + lm)*32 + csA]);
            #pragma unroll
            for (int i = 0; i < 4; ++i)
                #pragma unroll
                for (int j = 0; j < 2; ++j)
                    av[i][j] = __builtin_amdgcn_mfma_f32_16x16x32_bf16(af[i], bf[j], av[i][j], 0, 0, 0);
        }
        __builtin_amdgcn_s_barrier();
    }

    // epilogue Q: row-major Q2 with relu + sin/cos duplication
    #pragma unroll
    for (int i = 0; i < 4; ++i){
        #pragma unroll
        for (int q = 0; q < 4; ++q){
            int row = r0 + wr + i*16 + lq*4 + q;
            int n = row & (NN - 1);
            float sn = sc[n], cn = sc[NN + n];
            size_t base = (size_t)row * 1024 + c0 + wc + lm;
            #pragma unroll
            for (int j = 0; j < 2; ++j){
                float v = fmaxf(aq[i][j][q], 0.0f);
                Q2[base + j*16]       = f2b(sn * v);
                Q2[base + 512 + j*16] = f2b(cn * v);
            }
        }
    }
    // epilogue K: transposed, pre-scaled
    #pragma unroll
    for (int i = 0; i < 4; ++i){
        int rb = r0 + wr + i*16 + lq*4;
        int n  = rb & (NN - 1);
        float4 s4 = *reinterpret_cast<const float4*>(sc + n);
        float4 c4 = *reinterpret_cast<const float4*>(sc + NN + n);
        #pragma unroll
        for (int j = 0; j < 2; ++j){
            int d = c0 + wc + j*16 + lm;
            float v0 = fmaxf(ak[i][j][0], 0.f), v1 = fmaxf(ak[i][j][1], 0.f);
            float v2 = fmaxf(ak[i][j][2], 0.f), v3 = fmaxf(ak[i][j][3], 0.f);
            uint2 stS, stC;
            stS.x = pack2(v0*s4.x, v1*s4.y); stS.y = pack2(v2*s4.z, v3*s4.w);
            stC.x = pack2(v0*c4.x, v1*c4.y); stC.y = pack2(v2*c4.z, v3*c4.w);
            *reinterpret_cast<uint2*>(Ktsc + (size_t)d * BND + rb)         = stS;
            *reinterpret_cast<uint2*>(Ktsc + (size_t)(512 + d) * BND + rb) = stC;
        }
    }
    // epilogue V: transposed
    #pragma unroll
    for (int i = 0; i < 4; ++i){
        int rb = r0 + wr + i*16 + lq*4;
        #pragma unroll
        for (int j = 0; j < 2; ++j){
            int d = c0 + wc + j*16 + lm;
            uint2 st;
            st.x = pack2(av[i][j][0], av[i][j][1]);
            st.y = pack2(av[i][j][2], av[i][j][3]);
            *reinterpret_cast<uint2*>(Vt + (size_t)d * BND + rb) = st;
        }
    }
}

// ---------- kvp_part[sp][b][m][dp] = sum_{n in chunk} Vt[m,n]*Ktsc[dp,n]; PLAIN STORES ----------
__global__ __launch_bounds__(512) void k_kv(
    const unsigned short* __restrict__ Vt,
    const unsigned short* __restrict__ Ktsc,
    unsigned short* __restrict__ part)
{
    __shared__ __align__(16) unsigned short As[2][128*64];
    __shared__ __align__(16) unsigned short Bs[2][128*64];

    const int tid = threadIdx.x;
    const int m0  = blockIdx.x * 128;
    const int dp0 = blockIdx.y * 128;
    const int b   = blockIdx.z >> 2;
    const int sp  = blockIdx.z & 3;
    const int cb  = b * NN + sp * 1024;
    const int w  = tid >> 6, l = tid & 63;
    const int wr = (w >> 2) * 64, wc = (w & 3) * 32;
    const int lm = l & 15, lq = l >> 4;

    const unsigned short* aP = Vt   + (size_t)m0  * BND + cb;
    const unsigned short* bP = Ktsc + (size_t)dp0 * BND + cb;

    f32x4 acc[4][2];
    #pragma unroll
    for (int i = 0; i < 4; ++i)
        #pragma unroll
        for (int j = 0; j < 2; ++j)
            #pragma unroll
            for (int q = 0; q < 4; ++q) acc[i][j][q] = 0.0f;

    stageA128(aP, BND, As[0], w, l);
    stageA128(bP, BND, Bs[0], w, l);

    const int NT = 1024 / 64;   // 16
    for (int t = 0; t < NT; ++t){
        const int cur = t & 1;
        if (t + 1 < NT){
            stageA128(aP + (t+1)*64, BND, As[cur^1], w, l);
            stageA128(bP + (t+1)*64, BND, Bs[cur^1], w, l);
            waitvm4();
        } else {
            waitvm0();
        }
        __builtin_amdgcn_s_barrier();
        bf16x8 af[4][2], bf[2][2];
        #pragma unroll
        for (int h = 0; h < 2; ++h){
            const int cs = ((h*4 + lq) ^ (lm & 7)) * 8;
            #pragma unroll
            for (int i = 0; i < 4; ++i)
                af[i][h] = *reinterpret_cast<const bf16x8*>(&As[cur][(wr + i*16 + lm)*64 + cs]);
            #pragma unroll
            for (int j = 0; j < 2; ++j)
                bf[j][h] = *reinterpret_cast<const bf16x8*>(&Bs[cur][(wc + j*16 + lm)*64 + cs]);
        }
        #pragma unroll
        for (int h = 0; h < 2; ++h)
            #pragma unroll
            for (int i = 0; i < 4; ++i)
                #pragma unroll
                for (int j = 0; j < 2; ++j)
                    acc[i][j] = __builtin_amdgcn_mfma_f32_16x16x32_bf16(af[i][h], bf[j][h], acc[i][j], 0, 0, 0);
        __builtin_amdgcn_s_barrier();
    }

    // bf16 partial store, one writer per element: part[(sp*BB+b)*512 + m][dp]
    unsigned short* pp = part + ((size_t)(sp*BB + b) * 512) * 1024;
    #pragma unroll
    for (int i = 0; i < 4; ++i){
        #pragma unroll
        for (int q = 0; q < 4; ++q){
            int m = m0 + wr + i*16 + lq*4 + q;
            #pragma unroll
            for (int j = 0; j < 2; ++j){
                int dp = dp0 + wc + j*16 + lm;
                pp[(size_t)m*1024 + dp] = f2b(acc[i][j][q]);
            }
        }
    }
}

// ---------- kvb[b][m][dp] = sum_sp part[sp][b][m][dp] ----------
__global__ void k_red(const unsigned short* __restrict__ part,
                      unsigned short* __restrict__ kvb, int n8){
    int t = blockIdx.x * 256 + threadIdx.x;
    if (t < n8){
        const size_t stride = (size_t)BB*512*1024/8;   // per-sp span in uint4 units
        float f0[8], f1[8], f2[8], f3[8];
        unpack8(reinterpret_cast<const uint4*>(part)[t], f0);
        unpack8(reinterpret_cast<const uint4*>(part)[t + stride], f1);
        unpack8(reinterpret_cast<const uint4*>(part)[t + 2*stride], f2);
        unpack8(reinterpret_cast<const uint4*>(part)[t + 3*stride], f3);
        unsigned short r[8];
        #pragma unroll
        for (int u = 0; u < 8; ++u) r[u] = f2b(f0[u] + f1[u] + f2[u] + f3[u]);
        uint4 st;
        st.x = (unsigned int)r[0] | ((unsigned int)r[1] << 16);
        st.y = (unsigned int)r[2] | ((unsigned int)r[3] << 16);
        st.z = (unsigned int)r[4] | ((unsigned int)r[5] << 16);
        st.w = (unsigned int)r[6] | ((unsigned int)r[7] << 16);
        reinterpret_cast<uint4*>(kvb)[t] = st;
    }
}

// ---------- ksum[b][dp] = sum_n Ktsc[dp, b*NN+n] ----------
__global__ __launch_bounds__(256) void k_ksum(
    const unsigned short* __restrict__ Ktsc,
    float* __restrict__ ksum)
{
    int b = blockIdx.y;
    int dp = blockIdx.x * 4 + (threadIdx.x >> 6);
    int l = threadIdx.x & 63;
    const unsigned short* row = Ktsc + (size_t)dp * BND + b * NN;
    float ss = 0.f;
    for (int c0 = 0; c0 < NN; c0 += 512){
        float f[8];
        unpack8(*reinterpret_cast<const uint4*>(row + c0 + l*8), f);
        #pragma unroll
        for (int u = 0; u < 8; ++u) ss += f[u];
    }
    #pragma unroll
    for (int off = 32; off; off >>= 1) ss += __shfl_xor(ss, off);
    if (l == 0) ksum[b*1024 + dp] = ss;
}

// ---------- z[row] = 1/max(Q2[row,:].ksum[b,:], 1e-6) ----------
__global__ __launch_bounds__(256) void k_z(
    const unsigned short* __restrict__ Q2,
    const float* __restrict__ ksum,
    float* __restrict__ zden)
{
    int row  = blockIdx.x * 4 + (threadIdx.x >> 6);
    int lane = threadIdx.x & 63;
    int b = row >> 12;
    const unsigned short* qp = Q2 + (size_t)row * 1024 + lane * 16;
    float qf[16];
    unpack8(*reinterpret_cast<const uint4*>(qp), qf);
    unpack8(*reinterpret_cast<const uint4*>(qp + 8), qf + 8);
    const float* ks = ksum + (size_t)b*1024 + lane*16;
    float ps = 0.f;
    #pragma unroll
    for (int u = 0; u < 16; ++u) ps = fmaf(qf[u], ks[u], ps);
    #pragma unroll
    for (int off = 32; off; off >>= 1) ps += __shfl_xor(ps, off);
    if (lane == 0) zden[row] = 1.0f / fmaxf(ps, 1e-6f);
}

// ---------- out[n][m] = z * sum_dp Q2[n,dp]*kvb[b,m,dp]; 128x128 tiles; 8-wave ----------
__global__ __launch_bounds__(512) void k_out(
    const unsigned short* __restrict__ Q2,
    const unsigned short* __restrict__ kvb,
    const float* __restrict__ zden,
    float* __restrict__ Out)
{
    __shared__ __align__(16) unsigned short As[2][128*64];
    __shared__ __align__(16) unsigned short Bs[2][128*64];

    const int tid = threadIdx.x;
    const int r0 = blockIdx.x * 128;
    const int m0 = blockIdx.y * 128;
    const int b  = r0 >> 12;
    const int w  = tid >> 6, l = tid & 63;
    const int wr = (w >> 2) * 64, wc = (w & 3) * 32;
    const int lm = l & 15, lq = l >> 4;

    const unsigned short* aP = Q2 + (size_t)r0 * 1024;
    const unsigned short* bP = kvb + ((size_t)b*512 + m0) * 1024;

    f32x4 acc[4][2];
    #pragma unroll
    for (int i = 0; i < 4; ++i)
        #pragma unroll
        for (int j = 0; j < 2; ++j)
            #pragma unroll
            for (int q = 0; q < 4; ++q) acc[i][j][q] = 0.0f;

    stageA128(aP, 1024, As[0], w, l);
    stageA128(bP, 1024, Bs[0], w, l);

    const int NT = 1024 / 64;   // 16
    for (int t = 0; t < NT; ++t){
        const int cur = t & 1;
        if (t + 1 < NT){
            stageA128(aP + (t+1)*64, 1024, As[cur^1], w, l);
            stageA128(bP + (t+1)*64, 1024, Bs[cur^1], w, l);
            waitvm4();
        } else {
            waitvm0();
        }
        __builtin_amdgcn_s_barrier();
        bf16x8 af[4][2], bf[2][2];
        #pragma unroll
        for (int h = 0; h < 2; ++h){
            const int cs = ((h*4 + lq) ^ (lm & 7)) * 8;
            #pragma unroll
            for (int i = 0; i < 4; ++i)
                af[i][h] = *reinterpret_cast<const bf16x8*>(&As[cur][(wr + i*16 + lm)*64 + cs]);
            #pragma unroll
            for (int j = 0; j < 2; ++j)
                bf[j][h] = *reinterpret_cast<const bf16x8*>(&Bs[cur][(wc + j*16 + lm)*64 + cs]);
        }
        #pragma unroll
        for (int h = 0; h < 2; ++h)
            #pragma unroll
            for (int i = 0; i < 4; ++i)
                #pragma unroll
                for (int j = 0; j < 2; ++j)
                    acc[i][j] = __builtin_amdgcn_mfma_f32_16x16x32_bf16(af[i][h], bf[j][h], acc[i][j], 0, 0, 0);
        __builtin_amdgcn_s_barrier();
    }

    #pragma unroll
    for (int i = 0; i < 4; ++i){
        #pragma unroll
        for (int q = 0; q < 4; ++q){
            int grow = r0 + wr + i*16 + lq*4 + q;
            int n = grow & (NN - 1);
            float z  = zden[grow];
            int hh = n >> 9;
            int ttb = (n & 511) * 8;
            #pragma unroll
            for (int j = 0; j < 2; ++j){
                int m = m0 + wc + j*16 + lm;
                int tt = ttb + (m >> 6);
                Out[((size_t)b*NN + tt) * DD + hh*64 + (m & 63)] = acc[i][j][q] * z;
            }
        }
    }
}

extern "C" void kernel_launch(void* const* d_in, const int* in_sizes, int n_in,
                              void* d_out, int out_size, void* d_ws, size_t ws_size,
                              hipStream_t stream)
{
    const float* X  = (const float*)d_in[0];
    const float* Wq = (const float*)d_in[1];
    const float* Wk = (const float*)d_in[2];
    const float* Wv = (const float*)d_in[3];
    float* Out = (float*)d_out;

    char* p = (char*)d_ws;
    float* sincos = (float*)p; p += (size_t)2*NN*sizeof(float);
    float* ksum   = (float*)p; p += (size_t)BB*1024*sizeof(float);
    float* zden   = (float*)p; p += (size_t)BND*sizeof(float);
    // Xb (16 MB) is dead after k_qkv; kvp_part (16 MB bf16) aliases it.
    unsigned short* Xb   = (unsigned short*)p;
    unsigned short* part = (unsigned short*)p; p += (size_t)BND*DD*2;        // 16 MB shared
    unsigned short* Wqb  = (unsigned short*)p; p += (size_t)DD*DD*2;
    unsigned short* Wkb  = (unsigned short*)p; p += (size_t)DD*DD*2;
    unsigned short* Wvb  = (unsigned short*)p; p += (size_t)DD*DD*2;
    unsigned short* Q2   = (unsigned short*)p; p += (size_t)BND*1024*2;      // 32 MB
    unsigned short* Ktsc = (unsigned short*)p; p += (size_t)1024*BND*2;      // 32 MB
    unsigned short* Vt   = (unsigned short*)p; p += (size_t)512*BND*2;       // 16 MB
    unsigned short* kvb  = (unsigned short*)p; p += (size_t)BB*512*1024*2;   // 4 MB

    k_sincos<<<dim3(16), dim3(256), 0, stream>>>(sincos);
    k_cvt   <<<dim3(4096), dim3(256), 0, stream>>>(X,  Xb,  BND*DD/8);
    k_cvt   <<<dim3(128),  dim3(256), 0, stream>>>(Wq, Wqb, DD*DD/8);
    k_cvt   <<<dim3(128),  dim3(256), 0, stream>>>(Wk, Wkb, DD*DD/8);
    k_cvt   <<<dim3(128),  dim3(256), 0, stream>>>(Wv, Wvb, DD*DD/8);
    k_qkv   <<<dim3(BND/128, DD/128), dim3(512), 0, stream>>>(Xb, Wqb, Wkb, Wvb, sincos, Q2, Ktsc, Vt);
    k_kv    <<<dim3(4, 8, BB*4), dim3(512), 0, stream>>>(Vt, Ktsc, part);
    k_red   <<<dim3(1024), dim3(256), 0, stream>>>(part, kvb, BB*512*1024/8);
    k_ksum  <<<dim3(256, 4), dim3(256), 0, stream>>>(Ktsc, ksum);
    k_z     <<<dim3(BND/4), dim3(256), 0, stream>>>(Q2, ksum, zden);
    k_out   <<<dim3(BND/128, DD/128), dim3(512), 0, stream>>>(Q2, kvb, zden, Out);
}

// Round 14
// 135.155 us; speedup vs baseline: 1.4740x; 1.0153x over previous
//
#include <hip/hip_runtime.h>
#include <hip/hip_bf16.h>

#define BB 4
#define NN 4096
#define DD 512
#define BND (BB*NN)   // 16384

typedef __attribute__((ext_vector_type(8))) short bf16x8;
typedef __attribute__((ext_vector_type(4))) float f32x4;

// ---------- bf16 helpers ----------
__device__ __forceinline__ float b2f(unsigned int u){
    union { unsigned int u; float f; } c; c.u = u << 16; return c.f;
}
__device__ __forceinline__ unsigned short f2b(float f){
    union { float f; unsigned int u; } c; c.f = f;
    unsigned int r = c.u + 0x7fffu + ((c.u >> 16) & 1u);   // RNE
    return (unsigned short)(r >> 16);
}
__device__ __forceinline__ unsigned int pack2(float lo, float hi){
    __hip_bfloat162 h = __float22bfloat162_rn(make_float2(lo, hi));
    return *reinterpret_cast<unsigned int*>(&h);
}
__device__ __forceinline__ void unpack8(uint4 v, float* o){
    o[0]=b2f(v.x & 0xffffu); o[1]=b2f(v.x >> 16);
    o[2]=b2f(v.y & 0xffffu); o[3]=b2f(v.y >> 16);
    o[4]=b2f(v.z & 0xffffu); o[5]=b2f(v.z >> 16);
    o[6]=b2f(v.w & 0xffffu); o[7]=b2f(v.w >> 16);
}

// async global->LDS, 16B/lane; lds dest is wave-uniform base + lane*16
__device__ __forceinline__ void gload16(const void* g, void* l){
    __builtin_amdgcn_global_load_lds(
        (const __attribute__((address_space(1))) unsigned int*)g,
        (__attribute__((address_space(3))) unsigned int*)l,
        16, 0, 0);
}

// counted vmcnt waits (T4)
__device__ __forceinline__ void waitvm6(){ asm volatile("s_waitcnt vmcnt(6)" ::: "memory"); }
__device__ __forceinline__ void waitvm4(){ asm volatile("s_waitcnt vmcnt(4)" ::: "memory"); }
__device__ __forceinline__ void waitvm0(){ asm volatile("s_waitcnt vmcnt(0)" ::: "memory"); }

// ---- XOR-swizzled staging, 8-wave (512 threads), BK=64 (conflict-free 8-chunk) ----
// LDS rows of 64 bf16 (8 chunks x 16B); phys chunk c of row r = logical c^(r&7).
__device__ __forceinline__ void stageA128(const unsigned short* g, size_t gstride,
                                          unsigned short* lds, int w, int l){
    const int rr = l >> 3;
    const int sc = ((l & 7) ^ rr) * 8;
    const unsigned short* src = g + (size_t)(w*16 + rr) * gstride + sc;
    unsigned short* dst = lds + w*16*64;
    gload16(src,                       dst);
    gload16(src + (size_t)8*gstride,   dst + 8*64);
}

// ---------- sin/cos table ----------
__global__ void k_sincos(float* __restrict__ sc){
    int t = blockIdx.x * 256 + threadIdx.x;
    if (t < NN){
        float idx = 1.5707963267948966f * ((float)(t + 1) / (float)NN);
        sc[t]      = sinf(idx);
        sc[NN + t] = cosf(idx);
    }
}

// ---------- fp32 -> bf16 bulk convert ----------
__global__ void k_cvt(const float* __restrict__ in, unsigned short* __restrict__ out, int n8){
    int t = blockIdx.x * 256 + threadIdx.x;
    if (t < n8){
        float4 a = reinterpret_cast<const float4*>(in)[t*2];
        float4 b = reinterpret_cast<const float4*>(in)[t*2+1];
        uint4 st;
        st.x = pack2(a.x, a.y); st.y = pack2(a.z, a.w);
        st.z = pack2(b.x, b.y); st.w = pack2(b.z, b.w);
        reinterpret_cast<uint4*>(out)[t] = st;
    }
}

// ---------- q,k,v projections, unfused (z=3), BK=64, 64KB LDS, 2 blk/CU ----------
// which 0: Qb = relu(q) row-major [BND][512]
// which 1: Ktsc=[sin*k; cos*k] transposed [1024][BND]
// which 2: Vt transposed [512][BND]
__global__ __launch_bounds__(512) void k_qkv(
    const unsigned short* __restrict__ Xb,
    const unsigned short* __restrict__ Wqb,
    const unsigned short* __restrict__ Wkb,
    const unsigned short* __restrict__ Wvb,
    const float* __restrict__ sc,
    unsigned short* __restrict__ Qb,
    unsigned short* __restrict__ Ktsc,
    unsigned short* __restrict__ Vt)
{
    __shared__ __align__(16) unsigned short As[2][128*64];
    __shared__ __align__(16) unsigned short Bs[2][128*64];

    const int which = blockIdx.z;
    const unsigned short* W = (which == 0) ? Wqb : ((which == 1) ? Wkb : Wvb);

    const int tid = threadIdx.x;
    const int r0 = blockIdx.x * 128;
    const int c0 = blockIdx.y * 128;
    const int w  = tid >> 6, l = tid & 63;
    const int wr = (w >> 2) * 64;
    const int wc = (w & 3) * 32;
    const int lm = l & 15, lq = l >> 4;

    const unsigned short* aP = Xb + (size_t)r0 * DD;
    const unsigned short* bP = W  + (size_t)c0 * DD;

    f32x4 acc[4][2];
    #pragma unroll
    for (int i = 0; i < 4; ++i)
        #pragma unroll
        for (int j = 0; j < 2; ++j)
            #pragma unroll
            for (int q = 0; q < 4; ++q) acc[i][j][q] = 0.0f;

    stageA128(aP, DD, As[0], w, l);
    stageA128(bP, DD, Bs[0], w, l);

    const int NT = DD / 64;     // 8
    for (int t = 0; t < NT; ++t){
        const int cur = t & 1;
        if (t + 1 < NT){
            stageA128(aP + (t+1)*64, DD, As[cur^1], w, l);
            stageA128(bP + (t+1)*64, DD, Bs[cur^1], w, l);
            waitvm4();
        } else {
            waitvm0();
        }
        __builtin_amdgcn_s_barrier();
        bf16x8 af[4][2], bf[2][2];
        #pragma unroll
        for (int h = 0; h < 2; ++h){
            const int cs = ((h*4 + lq) ^ (lm & 7)) * 8;
            #pragma unroll
            for (int i = 0; i < 4; ++i)
                af[i][h] = *reinterpret_cast<const bf16x8*>(&As[cur][(wr + i*16 + lm)*64 + cs]);
            #pragma unroll
            for (int j = 0; j < 2; ++j)
                bf[j][h] = *reinterpret_cast<const bf16x8*>(&Bs[cur][(wc + j*16 + lm)*64 + cs]);
        }
        #pragma unroll
        for (int h = 0; h < 2; ++h)
            #pragma unroll
            for (int i = 0; i < 4; ++i)
                #pragma unroll
                for (int j = 0; j < 2; ++j)
                    acc[i][j] = __builtin_amdgcn_mfma_f32_16x16x32_bf16(af[i][h], bf[j][h], acc[i][j], 0, 0, 0);
        __builtin_amdgcn_s_barrier();
    }

    if (which == 0){
        // Qb: row-major relu(q), 512-wide
        #pragma unroll
        for (int i = 0; i < 4; ++i){
            #pragma unroll
            for (int q = 0; q < 4; ++q){
                int row = r0 + wr + i*16 + lq*4 + q;
                size_t base = (size_t)row * DD + c0 + wc + lm;
                #pragma unroll
                for (int j = 0; j < 2; ++j)
                    Qb[base + j*16] = f2b(fmaxf(acc[i][j][q], 0.0f));
            }
        }
    } else if (which == 1){
        #pragma unroll
        for (int i = 0; i < 4; ++i){
            int rb = r0 + wr + i*16 + lq*4;
            int n  = rb & (NN - 1);
            float4 s4 = *reinterpret_cast<const float4*>(sc + n);
            float4 c4 = *reinterpret_cast<const float4*>(sc + NN + n);
            #pragma unroll
            for (int j = 0; j < 2; ++j){
                int d = c0 + wc + j*16 + lm;
                float v0 = fmaxf(acc[i][j][0], 0.f), v1 = fmaxf(acc[i][j][1], 0.f);
                float v2 = fmaxf(acc[i][j][2], 0.f), v3 = fmaxf(acc[i][j][3], 0.f);
                uint2 stS, stC;
                stS.x = pack2(v0*s4.x, v1*s4.y); stS.y = pack2(v2*s4.z, v3*s4.w);
                stC.x = pack2(v0*c4.x, v1*c4.y); stC.y = pack2(v2*c4.z, v3*c4.w);
                *reinterpret_cast<uint2*>(Ktsc + (size_t)d * BND + rb)         = stS;
                *reinterpret_cast<uint2*>(Ktsc + (size_t)(512 + d) * BND + rb) = stC;
            }
        }
    } else {
        #pragma unroll
        for (int i = 0; i < 4; ++i){
            int rb = r0 + wr + i*16 + lq*4;
            #pragma unroll
            for (int j = 0; j < 2; ++j){
                int d = c0 + wc + j*16 + lm;
                uint2 st;
                st.x = pack2(acc[i][j][0], acc[i][j][1]);
                st.y = pack2(acc[i][j][2], acc[i][j][3]);
                *reinterpret_cast<uint2*>(Vt + (size_t)d * BND + rb) = st;
            }
        }
    }
}

// ---------- part[sp][b][m][dp] = sum_{n in chunk} Vt[m,n]*Ktsc[dp,n]; plain stores ----------
__global__ __launch_bounds__(512) void k_kv(
    const unsigned short* __restrict__ Vt,
    const unsigned short* __restrict__ Ktsc,
    unsigned short* __restrict__ part)
{
    __shared__ __align__(16) unsigned short As[2][128*64];
    __shared__ __align__(16) unsigned short Bs[2][128*64];

    const int tid = threadIdx.x;
    const int m0  = blockIdx.x * 128;
    const int dp0 = blockIdx.y * 128;
    const int b   = blockIdx.z >> 2;
    const int sp  = blockIdx.z & 3;
    const int cb  = b * NN + sp * 1024;
    const int w  = tid >> 6, l = tid & 63;
    const int wr = (w >> 2) * 64, wc = (w & 3) * 32;
    const int lm = l & 15, lq = l >> 4;

    const unsigned short* aP = Vt   + (size_t)m0  * BND + cb;
    const unsigned short* bP = Ktsc + (size_t)dp0 * BND + cb;

    f32x4 acc[4][2];
    #pragma unroll
    for (int i = 0; i < 4; ++i)
        #pragma unroll
        for (int j = 0; j < 2; ++j)
            #pragma unroll
            for (int q = 0; q < 4; ++q) acc[i][j][q] = 0.0f;

    stageA128(aP, BND, As[0], w, l);
    stageA128(bP, BND, Bs[0], w, l);

    const int NT = 1024 / 64;   // 16
    for (int t = 0; t < NT; ++t){
        const int cur = t & 1;
        if (t + 1 < NT){
            stageA128(aP + (t+1)*64, BND, As[cur^1], w, l);
            stageA128(bP + (t+1)*64, BND, Bs[cur^1], w, l);
            waitvm4();
        } else {
            waitvm0();
        }
        __builtin_amdgcn_s_barrier();
        bf16x8 af[4][2], bf[2][2];
        #pragma unroll
        for (int h = 0; h < 2; ++h){
            const int cs = ((h*4 + lq) ^ (lm & 7)) * 8;
            #pragma unroll
            for (int i = 0; i < 4; ++i)
                af[i][h] = *reinterpret_cast<const bf16x8*>(&As[cur][(wr + i*16 + lm)*64 + cs]);
            #pragma unroll
            for (int j = 0; j < 2; ++j)
                bf[j][h] = *reinterpret_cast<const bf16x8*>(&Bs[cur][(wc + j*16 + lm)*64 + cs]);
        }
        #pragma unroll
        for (int h = 0; h < 2; ++h)
            #pragma unroll
            for (int i = 0; i < 4; ++i)
                #pragma unroll
                for (int j = 0; j < 2; ++j)
                    acc[i][j] = __builtin_amdgcn_mfma_f32_16x16x32_bf16(af[i][h], bf[j][h], acc[i][j], 0, 0, 0);
        __builtin_amdgcn_s_barrier();
    }

    unsigned short* pp = part + ((size_t)(sp*BB + b) * 512) * 1024;
    #pragma unroll
    for (int i = 0; i < 4; ++i){
        #pragma unroll
        for (int q = 0; q < 4; ++q){
            int m = m0 + wr + i*16 + lq*4 + q;
            #pragma unroll
            for (int j = 0; j < 2; ++j){
                int dp = dp0 + wc + j*16 + lm;
                pp[(size_t)m*1024 + dp] = f2b(acc[i][j][q]);
            }
        }
    }
}

// ---------- kvb[b][m][dp] = sum_sp part[sp][b][m][dp] ----------
__global__ void k_red(const unsigned short* __restrict__ part,
                      unsigned short* __restrict__ kvb, int n8){
    int t = blockIdx.x * 256 + threadIdx.x;
    if (t < n8){
        const size_t stride = (size_t)BB*512*1024/8;
        float f0[8], f1[8], f2[8], f3[8];
        unpack8(reinterpret_cast<const uint4*>(part)[t], f0);
        unpack8(reinterpret_cast<const uint4*>(part)[t + stride], f1);
        unpack8(reinterpret_cast<const uint4*>(part)[t + 2*stride], f2);
        unpack8(reinterpret_cast<const uint4*>(part)[t + 3*stride], f3);
        unsigned short r[8];
        #pragma unroll
        for (int u = 0; u < 8; ++u) r[u] = f2b(f0[u] + f1[u] + f2[u] + f3[u]);
        uint4 st;
        st.x = (unsigned int)r[0] | ((unsigned int)r[1] << 16);
        st.y = (unsigned int)r[2] | ((unsigned int)r[3] << 16);
        st.z = (unsigned int)r[4] | ((unsigned int)r[5] << 16);
        st.w = (unsigned int)r[6] | ((unsigned int)r[7] << 16);
        reinterpret_cast<uint4*>(kvb)[t] = st;
    }
}

// ---------- ksum[b][dp] = sum_n Ktsc[dp, b*NN+n] ----------
__global__ __launch_bounds__(256) void k_ksum(
    const unsigned short* __restrict__ Ktsc,
    float* __restrict__ ksum)
{
    int b = blockIdx.y;
    int dp = blockIdx.x * 4 + (threadIdx.x >> 6);
    int l = threadIdx.x & 63;
    const unsigned short* row = Ktsc + (size_t)dp * BND + b * NN;
    float ss = 0.f;
    for (int c0 = 0; c0 < NN; c0 += 512){
        float f[8];
        unpack8(*reinterpret_cast<const uint4*>(row + c0 + l*8), f);
        #pragma unroll
        for (int u = 0; u < 8; ++u) ss += f[u];
    }
    #pragma unroll
    for (int off = 32; off; off >>= 1) ss += __shfl_xor(ss, off);
    if (l == 0) ksum[b*1024 + dp] = ss;
}

// ---------- z[row] = 1/max(sin_n*(q.ksum_s) + cos_n*(q.ksum_c), 1e-6) ----------
__global__ __launch_bounds__(256) void k_z(
    const unsigned short* __restrict__ Qb,
    const float* __restrict__ ksum, const float* __restrict__ sc,
    float* __restrict__ zden)
{
    int row  = blockIdx.x * 4 + (threadIdx.x >> 6);
    int lane = threadIdx.x & 63;
    int b = row >> 12, n = row & (NN - 1);
    uint4 qv = *reinterpret_cast<const uint4*>(Qb + (size_t)row * DD + lane * 8);
    float qf[8]; unpack8(qv, qf);
    const float* kss = ksum + (size_t)b*1024 + lane*8;
    const float* ksc = kss + 512;
    float ps = 0.f, pc = 0.f;
    #pragma unroll
    for (int u = 0; u < 8; ++u){ ps = fmaf(qf[u], kss[u], ps); pc = fmaf(qf[u], ksc[u], pc); }
    #pragma unroll
    for (int off = 32; off; off >>= 1){ ps += __shfl_xor(ps, off); pc += __shfl_xor(pc, off); }
    if (lane == 0){
        float den = sc[n]*ps + sc[NN+n]*pc;
        zden[row] = 1.0f / fmaxf(den, 1e-6f);
    }
}

// ---------- out[n][m] = z*(sin_n*(q@kvs) + cos_n*(q@kvc)); dual-B, K=512 ----------
__global__ __launch_bounds__(512) void k_out(
    const unsigned short* __restrict__ Qb,
    const unsigned short* __restrict__ kvb,
    const float* __restrict__ zden, const float* __restrict__ sc,
    float* __restrict__ Out)
{
    __shared__ __align__(16) unsigned short As[2][128*64];
    __shared__ __align__(16) unsigned short BsS[2][128*64];
    __shared__ __align__(16) unsigned short BsC[2][128*64];

    const int tid = threadIdx.x;
    const int r0 = blockIdx.x * 128;
    const int m0 = blockIdx.y * 128;
    const int b  = r0 >> 12;
    const int w  = tid >> 6, l = tid & 63;
    const int wr = (w >> 2) * 64, wc = (w & 3) * 32;
    const int lm = l & 15, lq = l >> 4;

    const unsigned short* aP  = Qb + (size_t)r0 * DD;
    const unsigned short* bPs = kvb + ((size_t)b*512 + m0) * 1024;        // sin half: cols 0..511
    const unsigned short* bPc = bPs + 512;                                 // cos half

    f32x4 accS[4][2], accC[4][2];
    #pragma unroll
    for (int i = 0; i < 4; ++i)
        #pragma unroll
        for (int j = 0; j < 2; ++j)
            #pragma unroll
            for (int q = 0; q < 4; ++q){ accS[i][j][q] = 0.f; accC[i][j][q] = 0.f; }

    stageA128(aP,  DD,   As[0],  w, l);
    stageA128(bPs, 1024, BsS[0], w, l);
    stageA128(bPc, 1024, BsC[0], w, l);

    const int NT = DD / 64;     // 8
    for (int t = 0; t < NT; ++t){
        const int cur = t & 1;
        if (t + 1 < NT){
            stageA128(aP  + (t+1)*64, DD,   As[cur^1],  w, l);
            stageA128(bPs + (t+1)*64, 1024, BsS[cur^1], w, l);
            stageA128(bPc + (t+1)*64, 1024, BsC[cur^1], w, l);
            waitvm6();
        } else {
            waitvm0();
        }
        __builtin_amdgcn_s_barrier();
        bf16x8 af[4][2], bs[2][2], bc[2][2];
        #pragma unroll
        for (int h = 0; h < 2; ++h){
            const int cs = ((h*4 + lq) ^ (lm & 7)) * 8;
            #pragma unroll
            for (int i = 0; i < 4; ++i)
                af[i][h] = *reinterpret_cast<const bf16x8*>(&As[cur][(wr + i*16 + lm)*64 + cs]);
            #pragma unroll
            for (int j = 0; j < 2; ++j){
                bs[j][h] = *reinterpret_cast<const bf16x8*>(&BsS[cur][(wc + j*16 + lm)*64 + cs]);
                bc[j][h] = *reinterpret_cast<const bf16x8*>(&BsC[cur][(wc + j*16 + lm)*64 + cs]);
            }
        }
        #pragma unroll
        for (int h = 0; h < 2; ++h)
            #pragma unroll
            for (int i = 0; i < 4; ++i)
                #pragma unroll
                for (int j = 0; j < 2; ++j){
                    accS[i][j] = __builtin_amdgcn_mfma_f32_16x16x32_bf16(af[i][h], bs[j][h], accS[i][j], 0, 0, 0);
                    accC[i][j] = __builtin_amdgcn_mfma_f32_16x16x32_bf16(af[i][h], bc[j][h], accC[i][j], 0, 0, 0);
                }
        __builtin_amdgcn_s_barrier();
    }

    #pragma unroll
    for (int i = 0; i < 4; ++i){
        #pragma unroll
        for (int q = 0; q < 4; ++q){
            int grow = r0 + wr + i*16 + lq*4 + q;
            int n = grow & (NN - 1);
            float z  = zden[grow];
            float sn = sc[n], cn = sc[NN + n];
            int hh = n >> 9;
            int ttb = (n & 511) * 8;
            #pragma unroll
            for (int j = 0; j < 2; ++j){
                int m = m0 + wc + j*16 + lm;
                int tt = ttb + (m >> 6);
                float v = (sn*accS[i][j][q] + cn*accC[i][j][q]) * z;
                Out[((size_t)b*NN + tt) * DD + hh*64 + (m & 63)] = v;
            }
        }
    }
}

extern "C" void kernel_launch(void* const* d_in, const int* in_sizes, int n_in,
                              void* d_out, int out_size, void* d_ws, size_t ws_size,
                              hipStream_t stream)
{
    const float* X  = (const float*)d_in[0];
    const float* Wq = (const float*)d_in[1];
    const float* Wk = (const float*)d_in[2];
    const float* Wv = (const float*)d_in[3];
    float* Out = (float*)d_out;

    char* p = (char*)d_ws;
    float* sincos = (float*)p; p += (size_t)2*NN*sizeof(float);
    float* ksum   = (float*)p; p += (size_t)BB*1024*sizeof(float);
    float* zden   = (float*)p; p += (size_t)BND*sizeof(float);
    // Xb (16 MB) dead after k_qkv; part (16 MB bf16) aliases it.
    unsigned short* Xb   = (unsigned short*)p;
    unsigned short* part = (unsigned short*)p; p += (size_t)BND*DD*2;        // 16 MB shared
    unsigned short* Wqb  = (unsigned short*)p; p += (size_t)DD*DD*2;
    unsigned short* Wkb  = (unsigned short*)p; p += (size_t)DD*DD*2;
    unsigned short* Wvb  = (unsigned short*)p; p += (size_t)DD*DD*2;
    unsigned short* Qb   = (unsigned short*)p; p += (size_t)BND*DD*2;        // 16 MB
    unsigned short* Ktsc = (unsigned short*)p; p += (size_t)1024*BND*2;      // 32 MB
    unsigned short* Vt   = (unsigned short*)p; p += (size_t)512*BND*2;       // 16 MB
    unsigned short* kvb  = (unsigned short*)p; p += (size_t)BB*512*1024*2;   // 4 MB

    k_sincos<<<dim3(16), dim3(256), 0, stream>>>(sincos);
    k_cvt   <<<dim3(4096), dim3(256), 0, stream>>>(X,  Xb,  BND*DD/8);
    k_cvt   <<<dim3(128),  dim3(256), 0, stream>>>(Wq, Wqb, DD*DD/8);
    k_cvt   <<<dim3(128),  dim3(256), 0, stream>>>(Wk, Wkb, DD*DD/8);
    k_cvt   <<<dim3(128),  dim3(256), 0, stream>>>(Wv, Wvb, DD*DD/8);
    k_qkv   <<<dim3(BND/128, DD/128, 3), dim3(512), 0, stream>>>(Xb, Wqb, Wkb, Wvb, sincos, Qb, Ktsc, Vt);
    k_kv    <<<dim3(4, 8, BB*4), dim3(512), 0, stream>>>(Vt, Ktsc, part);
    k_red   <<<dim3(1024), dim3(256), 0, stream>>>(part, kvb, BB*512*1024/8);
    k_ksum  <<<dim3(256, 4), dim3(256), 0, stream>>>(Ktsc, ksum);
    k_z     <<<dim3(BND/4), dim3(256), 0, stream>>>(Qb, ksum, sincos, zden);
    k_out   <<<dim3(BND/128, DD/128), dim3(512), 0, stream>>>(Qb, kvb, zden, sincos, Out);
}

// Round 18
// 124.459 us; speedup vs baseline: 1.6007x; 1.0859x over previous
//
#include <hip/hip_runtime.h>
#include <hip/hip_bf16.h>

#define BB 4
#define NN 4096
#define DD 512
#define BND (BB*NN)   // 16384

typedef __attribute__((ext_vector_type(8))) short bf16x8;
typedef __attribute__((ext_vector_type(4))) float f32x4;

// ---------- bf16 helpers ----------
__device__ __forceinline__ float b2f(unsigned int u){
    union { unsigned int u; float f; } c; c.u = u << 16; return c.f;
}
__device__ __forceinline__ unsigned short f2b(float f){
    union { float f; unsigned int u; } c; c.f = f;
    unsigned int r = c.u + 0x7fffu + ((c.u >> 16) & 1u);   // RNE
    return (unsigned short)(r >> 16);
}
__device__ __forceinline__ unsigned int pack2(float lo, float hi){
    __hip_bfloat162 h = __float22bfloat162_rn(make_float2(lo, hi));
    return *reinterpret_cast<unsigned int*>(&h);
}
__device__ __forceinline__ void unpack8(uint4 v, float* o){
    o[0]=b2f(v.x & 0xffffu); o[1]=b2f(v.x >> 16);
    o[2]=b2f(v.y & 0xffffu); o[3]=b2f(v.y >> 16);
    o[4]=b2f(v.z & 0xffffu); o[5]=b2f(v.z >> 16);
    o[6]=b2f(v.w & 0xffffu); o[7]=b2f(v.w >> 16);
}

// async global->LDS, 16B/lane; lds dest is wave-uniform base + lane*16
__device__ __forceinline__ void gload16(const void* g, void* l){
    __builtin_amdgcn_global_load_lds(
        (const __attribute__((address_space(1))) unsigned int*)g,
        (__attribute__((address_space(3))) unsigned int*)l,
        16, 0, 0);
}

// counted vmcnt waits (T4)
__device__ __forceinline__ void waitvm6(){ asm volatile("s_waitcnt vmcnt(6)" ::: "memory"); }
__device__ __forceinline__ void waitvm4(){ asm volatile("s_waitcnt vmcnt(4)" ::: "memory"); }
__device__ __forceinline__ void waitvm0(){ asm volatile("s_waitcnt vmcnt(0)" ::: "memory"); }

// ---- XOR-swizzled staging, 8-wave (512 threads), BK=64 (conflict-free 8-chunk) ----
// LDS rows of 64 bf16 (8 chunks x 16B); phys chunk c of row r = logical c^(r&7).
__device__ __forceinline__ void stageA128(const unsigned short* g, size_t gstride,
                                          unsigned short* lds, int w, int l){
    const int rr = l >> 3;
    const int sc = ((l & 7) ^ rr) * 8;
    const unsigned short* src = g + (size_t)(w*16 + rr) * gstride + sc;
    unsigned short* dst = lds + w*16*64;
    gload16(src,                       dst);
    gload16(src + (size_t)8*gstride,   dst + 8*64);
}

// ---------- fused cvt + sincos (range-partitioned single launch; exact partition) ----------
__device__ __forceinline__ void cvt8(const float* __restrict__ in,
                                     unsigned short* __restrict__ out, int t){
    float4 a = reinterpret_cast<const float4*>(in)[t*2];
    float4 b = reinterpret_cast<const float4*>(in)[t*2+1];
    uint4 st;
    st.x = pack2(a.x, a.y); st.y = pack2(a.z, a.w);
    st.z = pack2(b.x, b.y); st.w = pack2(b.z, b.w);
    reinterpret_cast<uint4*>(out)[t] = st;
}
__global__ void k_cvtall(const float* __restrict__ X,  const float* __restrict__ Wq,
                         const float* __restrict__ Wk, const float* __restrict__ Wv,
                         unsigned short* __restrict__ Xb,  unsigned short* __restrict__ Wqb,
                         unsigned short* __restrict__ Wkb, unsigned short* __restrict__ Wvb,
                         float* __restrict__ sc)
{
    const int NX = BND*DD/8, NW = DD*DD/8;
    int t = blockIdx.x * 256 + threadIdx.x;
    if (t < NX){ cvt8(X, Xb, t); return; }
    t -= NX;
    if (t < NW){ cvt8(Wq, Wqb, t); return; }
    t -= NW;
    if (t < NW){ cvt8(Wk, Wkb, t); return; }
    t -= NW;
    if (t < NW){ cvt8(Wv, Wvb, t); return; }
    t -= NW;
    if (t < NN){
        float idx = 1.5707963267948966f * ((float)(t + 1) / (float)NN);
        sc[t]      = sinf(idx);
        sc[NN + t] = cosf(idx);
    }
}

// ---------- q,k,v projections, unfused (z=3), BK=64, 64KB LDS, 2 blk/CU ----------
// which 0: Qb = relu(q) row-major [BND][512]
// which 1: Ktsc=[sin*k; cos*k] transposed [1024][BND]
// which 2: Vt transposed [512][BND]
// (round-14 verified epilogue: direct scattered uint2 stores)
__global__ __launch_bounds__(512) void k_qkv(
    const unsigned short* __restrict__ Xb,
    const unsigned short* __restrict__ Wqb,
    const unsigned short* __restrict__ Wkb,
    const unsigned short* __restrict__ Wvb,
    const float* __restrict__ sc,
    unsigned short* __restrict__ Qb,
    unsigned short* __restrict__ Ktsc,
    unsigned short* __restrict__ Vt)
{
    __shared__ __align__(16) unsigned short As[2][128*64];
    __shared__ __align__(16) unsigned short Bs[2][128*64];

    const int which = blockIdx.z;
    const unsigned short* W = (which == 0) ? Wqb : ((which == 1) ? Wkb : Wvb);

    const int tid = threadIdx.x;
    const int r0 = blockIdx.x * 128;
    const int c0 = blockIdx.y * 128;
    const int w  = tid >> 6, l = tid & 63;
    const int wr = (w >> 2) * 64;
    const int wc = (w & 3) * 32;
    const int lm = l & 15, lq = l >> 4;

    const unsigned short* aP = Xb + (size_t)r0 * DD;
    const unsigned short* bP = W  + (size_t)c0 * DD;

    f32x4 acc[4][2];
    #pragma unroll
    for (int i = 0; i < 4; ++i)
        #pragma unroll
        for (int j = 0; j < 2; ++j)
            #pragma unroll
            for (int q = 0; q < 4; ++q) acc[i][j][q] = 0.0f;

    stageA128(aP, DD, As[0], w, l);
    stageA128(bP, DD, Bs[0], w, l);

    const int NT = DD / 64;     // 8
    for (int t = 0; t < NT; ++t){
        const int cur = t & 1;
        if (t + 1 < NT){
            stageA128(aP + (t+1)*64, DD, As[cur^1], w, l);
            stageA128(bP + (t+1)*64, DD, Bs[cur^1], w, l);
            waitvm4();
        } else {
            waitvm0();
        }
        __builtin_amdgcn_s_barrier();
        bf16x8 af[4][2], bf[2][2];
        #pragma unroll
        for (int h = 0; h < 2; ++h){
            const int cs = ((h*4 + lq) ^ (lm & 7)) * 8;
            #pragma unroll
            for (int i = 0; i < 4; ++i)
                af[i][h] = *reinterpret_cast<const bf16x8*>(&As[cur][(wr + i*16 + lm)*64 + cs]);
            #pragma unroll
            for (int j = 0; j < 2; ++j)
                bf[j][h] = *reinterpret_cast<const bf16x8*>(&Bs[cur][(wc + j*16 + lm)*64 + cs]);
        }
        #pragma unroll
        for (int h = 0; h < 2; ++h)
            #pragma unroll
            for (int i = 0; i < 4; ++i)
                #pragma unroll
                for (int j = 0; j < 2; ++j)
                    acc[i][j] = __builtin_amdgcn_mfma_f32_16x16x32_bf16(af[i][h], bf[j][h], acc[i][j], 0, 0, 0);
        __builtin_amdgcn_s_barrier();
    }

    if (which == 0){
        // Qb: row-major relu(q), 512-wide
        #pragma unroll
        for (int i = 0; i < 4; ++i){
            #pragma unroll
            for (int q = 0; q < 4; ++q){
                int row = r0 + wr + i*16 + lq*4 + q;
                size_t base = (size_t)row * DD + c0 + wc + lm;
                #pragma unroll
                for (int j = 0; j < 2; ++j)
                    Qb[base + j*16] = f2b(fmaxf(acc[i][j][q], 0.0f));
            }
        }
    } else if (which == 1){
        #pragma unroll
        for (int i = 0; i < 4; ++i){
            int rb = r0 + wr + i*16 + lq*4;
            int n  = rb & (NN - 1);
            float4 s4 = *reinterpret_cast<const float4*>(sc + n);
            float4 c4 = *reinterpret_cast<const float4*>(sc + NN + n);
            #pragma unroll
            for (int j = 0; j < 2; ++j){
                int d = c0 + wc + j*16 + lm;
                float v0 = fmaxf(acc[i][j][0], 0.f), v1 = fmaxf(acc[i][j][1], 0.f);
                float v2 = fmaxf(acc[i][j][2], 0.f), v3 = fmaxf(acc[i][j][3], 0.f);
                uint2 stS, stC;
                stS.x = pack2(v0*s4.x, v1*s4.y); stS.y = pack2(v2*s4.z, v3*s4.w);
                stC.x = pack2(v0*c4.x, v1*c4.y); stC.y = pack2(v2*c4.z, v3*c4.w);
                *reinterpret_cast<uint2*>(Ktsc + (size_t)d * BND + rb)         = stS;
                *reinterpret_cast<uint2*>(Ktsc + (size_t)(512 + d) * BND + rb) = stC;
            }
        }
    } else {
        #pragma unroll
        for (int i = 0; i < 4; ++i){
            int rb = r0 + wr + i*16 + lq*4;
            #pragma unroll
            for (int j = 0; j < 2; ++j){
                int d = c0 + wc + j*16 + lm;
                uint2 st;
                st.x = pack2(acc[i][j][0], acc[i][j][1]);
                st.y = pack2(acc[i][j][2], acc[i][j][3]);
                *reinterpret_cast<uint2*>(Vt + (size_t)d * BND + rb) = st;
            }
        }
    }
}

// ---------- part[sp][b][m][dp] = sum_{n in chunk} Vt[m,n]*Ktsc[dp,n]; plain stores ----------
__global__ __launch_bounds__(512) void k_kv(
    const unsigned short* __restrict__ Vt,
    const unsigned short* __restrict__ Ktsc,
    unsigned short* __restrict__ part)
{
    __shared__ __align__(16) unsigned short As[2][128*64];
    __shared__ __align__(16) unsigned short Bs[2][128*64];

    const int tid = threadIdx.x;
    const int m0  = blockIdx.x * 128;
    const int dp0 = blockIdx.y * 128;
    const int b   = blockIdx.z >> 2;
    const int sp  = blockIdx.z & 3;
    const int cb  = b * NN + sp * 1024;
    const int w  = tid >> 6, l = tid & 63;
    const int wr = (w >> 2) * 64, wc = (w & 3) * 32;
    const int lm = l & 15, lq = l >> 4;

    const unsigned short* aP = Vt   + (size_t)m0  * BND + cb;
    const unsigned short* bP = Ktsc + (size_t)dp0 * BND + cb;

    f32x4 acc[4][2];
    #pragma unroll
    for (int i = 0; i < 4; ++i)
        #pragma unroll
        for (int j = 0; j < 2; ++j)
            #pragma unroll
            for (int q = 0; q < 4; ++q) acc[i][j][q] = 0.0f;

    stageA128(aP, BND, As[0], w, l);
    stageA128(bP, BND, Bs[0], w, l);

    const int NT = 1024 / 64;   // 16
    for (int t = 0; t < NT; ++t){
        const int cur = t & 1;
        if (t + 1 < NT){
            stageA128(aP + (t+1)*64, BND, As[cur^1], w, l);
            stageA128(bP + (t+1)*64, BND, Bs[cur^1], w, l);
            waitvm4();
        } else {
            waitvm0();
        }
        __builtin_amdgcn_s_barrier();
        bf16x8 af[4][2], bf[2][2];
        #pragma unroll
        for (int h = 0; h < 2; ++h){
            const int cs = ((h*4 + lq) ^ (lm & 7)) * 8;
            #pragma unroll
            for (int i = 0; i < 4; ++i)
                af[i][h] = *reinterpret_cast<const bf16x8*>(&As[cur][(wr + i*16 + lm)*64 + cs]);
            #pragma unroll
            for (int j = 0; j < 2; ++j)
                bf[j][h] = *reinterpret_cast<const bf16x8*>(&Bs[cur][(wc + j*16 + lm)*64 + cs]);
        }
        #pragma unroll
        for (int h = 0; h < 2; ++h)
            #pragma unroll
            for (int i = 0; i < 4; ++i)
                #pragma unroll
                for (int j = 0; j < 2; ++j)
                    acc[i][j] = __builtin_amdgcn_mfma_f32_16x16x32_bf16(af[i][h], bf[j][h], acc[i][j], 0, 0, 0);
        __builtin_amdgcn_s_barrier();
    }

    unsigned short* pp = part + ((size_t)(sp*BB + b) * 512) * 1024;
    #pragma unroll
    for (int i = 0; i < 4; ++i){
        #pragma unroll
        for (int q = 0; q < 4; ++q){
            int m = m0 + wr + i*16 + lq*4 + q;
            #pragma unroll
            for (int j = 0; j < 2; ++j){
                int dp = dp0 + wc + j*16 + lm;
                pp[(size_t)m*1024 + dp] = f2b(acc[i][j][q]);
            }
        }
    }
}

// ---------- kvb[b][m][dp] = sum_sp part[sp][b][m][dp] ----------
__global__ void k_red(const unsigned short* __restrict__ part,
                      unsigned short* __restrict__ kvb, int n8){
    int t = blockIdx.x * 256 + threadIdx.x;
    if (t < n8){
        const size_t stride = (size_t)BB*512*1024/8;
        float f0[8], f1[8], f2[8], f3[8];
        unpack8(reinterpret_cast<const uint4*>(part)[t], f0);
        unpack8(reinterpret_cast<const uint4*>(part)[t + stride], f1);
        unpack8(reinterpret_cast<const uint4*>(part)[t + 2*stride], f2);
        unpack8(reinterpret_cast<const uint4*>(part)[t + 3*stride], f3);
        unsigned short r[8];
        #pragma unroll
        for (int u = 0; u < 8; ++u) r[u] = f2b(f0[u] + f1[u] + f2[u] + f3[u]);
        uint4 st;
        st.x = (unsigned int)r[0] | ((unsigned int)r[1] << 16);
        st.y = (unsigned int)r[2] | ((unsigned int)r[3] << 16);
        st.z = (unsigned int)r[4] | ((unsigned int)r[5] << 16);
        st.w = (unsigned int)r[6] | ((unsigned int)r[7] << 16);
        reinterpret_cast<uint4*>(kvb)[t] = st;
    }
}

// ---------- ksum[b][dp] = sum_n Ktsc[dp, b*NN+n] ----------
__global__ __launch_bounds__(256) void k_ksum(
    const unsigned short* __restrict__ Ktsc,
    float* __restrict__ ksum)
{
    int b = blockIdx.y;
    int dp = blockIdx.x * 4 + (threadIdx.x >> 6);
    int l = threadIdx.x & 63;
    const unsigned short* row = Ktsc + (size_t)dp * BND + b * NN;
    float ss = 0.f;
    for (int c0 = 0; c0 < NN; c0 += 512){
        float f[8];
        unpack8(*reinterpret_cast<const uint4*>(row + c0 + l*8), f);
        #pragma unroll
        for (int u = 0; u < 8; ++u) ss += f[u];
    }
    #pragma unroll
    for (int off = 32; off; off >>= 1) ss += __shfl_xor(ss, off);
    if (l == 0) ksum[b*1024 + dp] = ss;
}

// ---------- z[row] = 1/max(sin_n*(q.ksum_s) + cos_n*(q.ksum_c), 1e-6) ----------
__global__ __launch_bounds__(256) void k_z(
    const unsigned short* __restrict__ Qb,
    const float* __restrict__ ksum, const float* __restrict__ sc,
    float* __restrict__ zden)
{
    int row  = blockIdx.x * 4 + (threadIdx.x >> 6);
    int lane = threadIdx.x & 63;
    int b = row >> 12, n = row & (NN - 1);
    uint4 qv = *reinterpret_cast<const uint4*>(Qb + (size_t)row * DD + lane * 8);
    float qf[8]; unpack8(qv, qf);
    const float* kss = ksum + (size_t)b*1024 + lane*8;
    const float* ksc = kss + 512;
    float ps = 0.f, pc = 0.f;
    #pragma unroll
    for (int u = 0; u < 8; ++u){ ps = fmaf(qf[u], kss[u], ps); pc = fmaf(qf[u], ksc[u], pc); }
    #pragma unroll
    for (int off = 32; off; off >>= 1){ ps += __shfl_xor(ps, off); pc += __shfl_xor(pc, off); }
    if (lane == 0){
        float den = sc[n]*ps + sc[NN+n]*pc;
        zden[row] = 1.0f / fmaxf(den, 1e-6f);
    }
}

// ---------- out[n][m] = z*(sin_n*(q@kvs) + cos_n*(q@kvc)); dual-B, K=512 ----------
__global__ __launch_bounds__(512) void k_out(
    const unsigned short* __restrict__ Qb,
    const unsigned short* __restrict__ kvb,
    const float* __restrict__ zden, const float* __restrict__ sc,
    float* __restrict__ Out)
{
    __shared__ __align__(16) unsigned short As[2][128*64];
    __shared__ __align__(16) unsigned short BsS[2][128*64];
    __shared__ __align__(16) unsigned short BsC[2][128*64];

    const int tid = threadIdx.x;
    const int r0 = blockIdx.x * 128;
    const int m0 = blockIdx.y * 128;
    const int b  = r0 >> 12;
    const int w  = tid >> 6, l = tid & 63;
    const int wr = (w >> 2) * 64, wc = (w & 3) * 32;
    const int lm = l & 15, lq = l >> 4;

    const unsigned short* aP  = Qb + (size_t)r0 * DD;
    const unsigned short* bPs = kvb + ((size_t)b*512 + m0) * 1024;
    const unsigned short* bPc = bPs + 512;

    f32x4 accS[4][2], accC[4][2];
    #pragma unroll
    for (int i = 0; i < 4; ++i)
        #pragma unroll
        for (int j = 0; j < 2; ++j)
            #pragma unroll
            for (int q = 0; q < 4; ++q){ accS[i][j][q] = 0.f; accC[i][j][q] = 0.f; }

    stageA128(aP,  DD,   As[0],  w, l);
    stageA128(bPs, 1024, BsS[0], w, l);
    stageA128(bPc, 1024, BsC[0], w, l);

    const int NT = DD / 64;     // 8
    for (int t = 0; t < NT; ++t){
        const int cur = t & 1;
        if (t + 1 < NT){
            stageA128(aP  + (t+1)*64, DD,   As[cur^1],  w, l);
            stageA128(bPs + (t+1)*64, 1024, BsS[cur^1], w, l);
            stageA128(bPc + (t+1)*64, 1024, BsC[cur^1], w, l);
            waitvm6();
        } else {
            waitvm0();
        }
        __builtin_amdgcn_s_barrier();
        bf16x8 af[4][2], bs[2][2], bc[2][2];
        #pragma unroll
        for (int h = 0; h < 2; ++h){
            const int cs = ((h*4 + lq) ^ (lm & 7)) * 8;
            #pragma unroll
            for (int i = 0; i < 4; ++i)
                af[i][h] = *reinterpret_cast<const bf16x8*>(&As[cur][(wr + i*16 + lm)*64 + cs]);
            #pragma unroll
            for (int j = 0; j < 2; ++j){
                bs[j][h] = *reinterpret_cast<const bf16x8*>(&BsS[cur][(wc + j*16 + lm)*64 + cs]);
                bc[j][h] = *reinterpret_cast<const bf16x8*>(&BsC[cur][(wc + j*16 + lm)*64 + cs]);
            }
        }
        #pragma unroll
        for (int h = 0; h < 2; ++h)
            #pragma unroll
            for (int i = 0; i < 4; ++i)
                #pragma unroll
                for (int j = 0; j < 2; ++j){
                    accS[i][j] = __builtin_amdgcn_mfma_f32_16x16x32_bf16(af[i][h], bs[j][h], accS[i][j], 0, 0, 0);
                    accC[i][j] = __builtin_amdgcn_mfma_f32_16x16x32_bf16(af[i][h], bc[j][h], accC[i][j], 0, 0, 0);
                }
        __builtin_amdgcn_s_barrier();
    }

    #pragma unroll
    for (int i = 0; i < 4; ++i){
        #pragma unroll
        for (int q = 0; q < 4; ++q){
            int grow = r0 + wr + i*16 + lq*4 + q;
            int n = grow & (NN - 1);
            float z  = zden[grow];
            float sn = sc[n], cn = sc[NN + n];
            int hh = n >> 9;
            int ttb = (n & 511) * 8;
            #pragma unroll
            for (int j = 0; j < 2; ++j){
                int m = m0 + wc + j*16 + lm;
                int tt = ttb + (m >> 6);
                float v = (sn*accS[i][j][q] + cn*accC[i][j][q]) * z;
                Out[((size_t)b*NN + tt) * DD + hh*64 + (m & 63)] = v;
            }
        }
    }
}

extern "C" void kernel_launch(void* const* d_in, const int* in_sizes, int n_in,
                              void* d_out, int out_size, void* d_ws, size_t ws_size,
                              hipStream_t stream)
{
    const float* X  = (const float*)d_in[0];
    const float* Wq = (const float*)d_in[1];
    const float* Wk = (const float*)d_in[2];
    const float* Wv = (const float*)d_in[3];
    float* Out = (float*)d_out;

    char* p = (char*)d_ws;
    float* sincos = (float*)p; p += (size_t)2*NN*sizeof(float);
    float* ksum   = (float*)p; p += (size_t)BB*1024*sizeof(float);
    float* zden   = (float*)p; p += (size_t)BND*sizeof(float);
    // Xb (16 MB) dead after k_qkv; part (16 MB bf16) aliases it.
    unsigned short* Xb   = (unsigned short*)p;
    unsigned short* part = (unsigned short*)p; p += (size_t)BND*DD*2;        // 16 MB shared
    unsigned short* Wqb  = (unsigned short*)p; p += (size_t)DD*DD*2;
    unsigned short* Wkb  = (unsigned short*)p; p += (size_t)DD*DD*2;
    unsigned short* Wvb  = (unsigned short*)p; p += (size_t)DD*DD*2;
    unsigned short* Qb   = (unsigned short*)p; p += (size_t)BND*DD*2;        // 16 MB
    unsigned short* Ktsc = (unsigned short*)p; p += (size_t)1024*BND*2;      // 32 MB
    unsigned short* Vt   = (unsigned short*)p; p += (size_t)512*BND*2;       // 16 MB
    unsigned short* kvb  = (unsigned short*)p; p += (size_t)BB*512*1024*2;   // 4 MB

    const int NBLK = (BND*DD/8 + 3*(DD*DD/8) + NN + 255) / 256;
    k_cvtall<<<dim3(NBLK), dim3(256), 0, stream>>>(X, Wq, Wk, Wv, Xb, Wqb, Wkb, Wvb, sincos);
    k_qkv   <<<dim3(BND/128, DD/128, 3), dim3(512), 0, stream>>>(Xb, Wqb, Wkb, Wvb, sincos, Qb, Ktsc, Vt);
    k_kv    <<<dim3(4, 8, BB*4), dim3(512), 0, stream>>>(Vt, Ktsc, part);
    k_red   <<<dim3(1024), dim3(256), 0, stream>>>(part, kvb, BB*512*1024/8);
    k_ksum  <<<dim3(256, 4), dim3(256), 0, stream>>>(Ktsc, ksum);
    k_z     <<<dim3(BND/4), dim3(256), 0, stream>>>(Qb, ksum, sincos, zden);
    k_out   <<<dim3(BND/128, DD/128), dim3(512), 0, stream>>>(Qb, kvb, zden, sincos, Out);
}